// Round 2
// baseline (491.945 us; speedup 1.0000x reference)
//
#include <hip/hip_runtime.h>
#include <math.h>

typedef unsigned short u16;
typedef unsigned int u32;

// B=8, C=256, H=W=64, L=4096, NH=8, HD=32
static constexpr float SCALE = 0.17677669529663687f;          // 1/sqrt(32)
static constexpr float C2    = 0.17677669529663687f / 4096.f; // (scale/L) = c^2

__device__ __forceinline__ float bf2f(u16 u){
  union { u32 i; float f; } v; v.i = ((u32)u) << 16; return v.f;
}
__device__ __forceinline__ u16 f2bf(float f){
  union { float fl; u32 i; } v; v.fl = f;
  u32 r = v.i + 0x7fffu + ((v.i >> 16) & 1u);   // round-to-nearest-even
  return (u16)(r >> 16);
}
__device__ __forceinline__ float eluP(float x){  // elu(x)+1
  return x > 0.f ? x + 1.f : expf(x);
}
// freq table: 10000^(-j/7), j=0..7 (matches rope_sincos's linspace)
__device__ __forceinline__ float rfreq(int j){
  const float t[8] = {1.f, 0.2682695795f, 0.0719685673f, 0.0193069773f,
                      0.0051794747f, 0.0013894955f, 0.0003727594f, 1e-4f};
  return t[j];
}
// pair p in 0..15 (channels 2p,2p+1); first 8 pairs use h=l>>6, rest w=l&63
__device__ __forceinline__ void rope_sc(int p, int l, float* sn, float* cs){
  int pos = (p < 8) ? (l >> 6) : (l & 63);
  float th = rfreq(p & 7) * (float)pos;
  sincosf(th, sn, cs);
}

// ---------------- input dtype detect: 1 = fp32, 0 = bf16 ----------------
// Scans first 8192 u16 of qkvo_w (random ~0.02*N(0,1) either dtype).
// bf16 weights: exponent field in ~[0x71,0x7B] -> count ~0.
// fp32 weights read as u16: even elements are random mantissa bits -> ~44% hit.
__global__ __launch_bounds__(256) void k_detect(const u16* __restrict__ qw, int* flag){
  __shared__ int cnt;
  if (threadIdx.x == 0) cnt = 0;
  __syncthreads();
  int c = 0;
  for (int i = threadIdx.x; i < 8192; i += 256){
    int e = (qw[i] >> 7) & 0xFF;
    if (e >= 0x90 || e == 0) c++;
  }
  atomicAdd(&cnt, c);
  __syncthreads();
  if (threadIdx.x == 0) *flag = (cnt > 64) ? 1 : 0;
}

// ---------------- weight prep: transpose to k-major + convert to fp32 ----------------
__global__ __launch_bounds__(256) void k_prep(
    const void* __restrict__ qw, const void* __restrict__ pw,
    const void* __restrict__ qb, const void* __restrict__ lw,
    const void* __restrict__ lb, const void* __restrict__ pb,
    const int* __restrict__ flag,
    float* __restrict__ WtA, float* __restrict__ WtP,
    float* __restrict__ qbF, float* __restrict__ lwF,
    float* __restrict__ lbF, float* __restrict__ pbF)
{
  const bool f32 = (*flag != 0);
  int idx = blockIdx.x * 256 + threadIdx.x;
  if (idx < 262144){              // qkvo_w (1024,256): WtA[k][m]
    int m = idx >> 8, k = idx & 255;
    WtA[k * 1024 + m] = f32 ? ((const float*)qw)[idx] : bf2f(((const u16*)qw)[idx]);
  }
  if (idx < 65536){               // proj_w (256,256): WtP[k][m]
    int m = idx >> 8, k = idx & 255;
    WtP[k * 256 + m] = f32 ? ((const float*)pw)[idx] : bf2f(((const u16*)pw)[idx]);
  }
  if (idx < 6400) lwF[idx] = f32 ? ((const float*)lw)[idx] : bf2f(((const u16*)lw)[idx]);
  if (idx < 1024) qbF[idx] = f32 ? ((const float*)qb)[idx] : bf2f(((const u16*)qb)[idx]);
  if (idx < 256){
    lbF[idx] = f32 ? ((const float*)lb)[idx] : bf2f(((const u16*)lb)[idx]);
    pbF[idx] = f32 ? ((const float*)pb)[idx] : bf2f(((const u16*)pb)[idx]);
  }
}

// ---------------- x -> fp32 ----------------
__global__ __launch_bounds__(256) void k_cvtx(
    const void* __restrict__ x, const int* __restrict__ flag, float* __restrict__ Xf)
{
  long i = (long)blockIdx.x * 256 + threadIdx.x;
  Xf[i] = (*flag != 0) ? ((const float*)x)[i] : bf2f(((const u16*)x)[i]);
}

// ---------------- qkvo GEMM: out[b][o][l] = sum_c W[o][c] x[b][c][l] ----------------
// grid (64 ntiles, 16 mtiles, 8 b), 256 thr, tile 64x64, BK=32
__global__ __launch_bounds__(256) void k_gemm_qkvo(
    const float* __restrict__ Wt,      // [256][1024] fp32 (k-major)
    const float* __restrict__ Xf,      // [8][256][4096] fp32
    const float* __restrict__ bias,    // [1024] fp32
    float* __restrict__ Q0, float* __restrict__ K0,
    float* __restrict__ Vb, float* __restrict__ Ob)
{
  __shared__ float As[32][68];
  __shared__ float Bs[32][68];
  const int tid = threadIdx.x;
  const int b = blockIdx.z, mt = blockIdx.y, nt = blockIdx.x;
  const int m0g = mt * 64, n0g = nt * 64;
  const int tm = tid >> 4, tn = tid & 15;

  float acc[4][4];
  #pragma unroll
  for (int i=0;i<4;i++){ acc[i][0]=0.f; acc[i][1]=0.f; acc[i][2]=0.f; acc[i][3]=0.f; }

  const float* xp = Xf + (((long)b * 256) << 12);

  for (int kk = 0; kk < 256; kk += 32){
    #pragma unroll
    for (int r = 0; r < 2; r++){
      int idx = tid + r * 256;
      int k = idx >> 4, mj = (idx & 15) * 4;
      *(float4*)&As[k][mj] = *(const float4*)&Wt[(kk + k) * 1024 + m0g + mj];
    }
    #pragma unroll
    for (int r = 0; r < 2; r++){
      int idx = tid + r * 256;
      int k = idx >> 4, nj = (idx & 15) * 4;
      *(float4*)&Bs[k][nj] = *(const float4*)(xp + (((long)(kk + k)) << 12) + n0g + nj);
    }
    __syncthreads();
    #pragma unroll
    for (int k = 0; k < 32; k++){
      float4 av = *(float4*)&As[k][tm * 4];
      float4 bv = *(float4*)&Bs[k][tn * 4];
      float aa[4] = {av.x, av.y, av.z, av.w};
      float bb[4] = {bv.x, bv.y, bv.z, bv.w};
      #pragma unroll
      for (int i=0;i<4;i++)
        #pragma unroll
        for (int j=0;j<4;j++) acc[i][j] += aa[i] * bb[j];
    }
    __syncthreads();
  }

  const int range = mt >> 2;                   // 0:q 1:k 2:v 3:o
  const int chBase = (mt & 3) * 64 + tm * 4;
  float* dst = (range == 0) ? Q0 : (range == 1) ? K0 : (range == 2) ? Vb : Ob;
  #pragma unroll
  for (int i = 0; i < 4; i++){
    const float bia = bias[m0g + tm * 4 + i];
    float4 v;
    v.x = acc[i][0] + bia; v.y = acc[i][1] + bia;
    v.z = acc[i][2] + bia; v.w = acc[i][3] + bia;
    if (range < 2){ v.x = eluP(v.x); v.y = eluP(v.y); v.z = eluP(v.z); v.w = eluP(v.w); }
    float* o = dst + (((long)b * 256 + chBase + i) << 12) + n0g + tn * 4;
    *(float4*)o = v;
  }
}

// ---------------- channel means over L ----------------
__global__ __launch_bounds__(256) void k_means(
    const float* __restrict__ K0, const float* __restrict__ Vb,
    float* __restrict__ KMb, float* __restrict__ VMb)
{
  int ch = blockIdx.x, b = blockIdx.y, which = blockIdx.z;
  const float* src = (which ? Vb : K0) + (((long)b * 256 + ch) << 12);
  float s = 0.f;
  for (int i = threadIdx.x; i < 4096; i += 256) s += src[i];
  #pragma unroll
  for (int off = 32; off > 0; off >>= 1) s += __shfl_down(s, off);
  __shared__ float red[4];
  if ((threadIdx.x & 63) == 0) red[threadIdx.x >> 6] = s;
  __syncthreads();
  if (threadIdx.x == 0)
    (which ? VMb : KMb)[b * 256 + ch] = (red[0]+red[1]+red[2]+red[3]) * (1.f/4096.f);
}

// ---------------- z[b,n,l] = scale * sum_d q[d][l] * kmean[d] ----------------
__global__ __launch_bounds__(256) void k_z(
    const float* __restrict__ Q0, const float* __restrict__ KMb, float* __restrict__ Zb)
{
  int b = blockIdx.z, n = blockIdx.y;
  int l = blockIdx.x * 256 + threadIdx.x;
  const float* qp = Q0 + (((long)b * 256 + n * 32) << 12) + l;
  const float* km = KMb + b * 256 + n * 32;
  float s = 0.f;
  #pragma unroll
  for (int d = 0; d < 32; d++) s += qp[d << 12] * km[d];
  Zb[((b * 8 + n) << 12) + l] = s * SCALE;
}

// ---------------- kv[b,n,d,e] = c2 * sum_l ropeK[d][l] * V[e][l] ----------------
// grid (8 lsplit, 8 n, 8 b); fp32 atomics into zeroed KVb
__global__ __launch_bounds__(256) void k_kv(
    const float* __restrict__ K0, const float* __restrict__ Vb, float* __restrict__ KVb)
{
  __shared__ float Kl[32][65];
  __shared__ float Vl[32][65];
  int b = blockIdx.z, n = blockIdx.y, ls = blockIdx.x;
  int tid = threadIdx.x;
  const float* kp = K0 + (((long)b * 256 + n * 32) << 12);
  const float* vp = Vb + (((long)b * 256 + n * 32) << 12);
  int lane = tid & 63, grp = tid >> 6;
  int eg = tid & 15, dg = tid >> 4;
  float a00=0.f, a01=0.f, a10=0.f, a11=0.f;

  for (int l0 = ls * 512; l0 < ls * 512 + 512; l0 += 64){
    int lg = l0 + lane;
    #pragma unroll
    for (int r = 0; r < 4; r++){
      int p = grp + (r << 2);                  // pair 0..15
      float k0 = kp[((2*p) << 12) + lg];
      float k1 = kp[((2*p+1) << 12) + lg];
      float sn, cs; rope_sc(p, lg, &sn, &cs);
      Kl[2*p][lane]   = k0 * cs - k1 * sn;
      Kl[2*p+1][lane] = k1 * cs + k0 * sn;
    }
    #pragma unroll
    for (int r = 0; r < 8; r++){
      int ch = grp + (r << 2);                 // 0..31
      Vl[ch][lane] = vp[(ch << 12) + lg];
    }
    __syncthreads();
    #pragma unroll
    for (int l = 0; l < 64; l++){
      float v0 = Vl[eg][l], v1 = Vl[eg + 16][l];
      float kA = Kl[dg][l], kB = Kl[dg + 16][l];
      a00 += kA * v0; a01 += kA * v1;
      a10 += kB * v0; a11 += kB * v1;
    }
    __syncthreads();
  }
  float* dst = KVb + (((long)b * 8 + n) << 10);
  atomicAdd(&dst[dg * 32 + eg],             a00 * C2);
  atomicAdd(&dst[dg * 32 + eg + 16],        a01 * C2);
  atomicAdd(&dst[(dg + 16) * 32 + eg],      a10 * C2);
  atomicAdd(&dst[(dg + 16) * 32 + eg + 16], a11 * C2);
}

// ---------------- lepe = depthwise 5x5 (pad 2) of V -> Tb ----------------
__global__ __launch_bounds__(256) void k_lepe(
    const float* __restrict__ Vb, const float* __restrict__ lwF,
    const float* __restrict__ lbF, float* __restrict__ Tb)
{
  __shared__ float tile[20][68];
  __shared__ float wl[25];
  int ht = blockIdx.x, ch = blockIdx.y, b = blockIdx.z;
  int h0 = ht * 16;
  const float* vp = Vb + (((long)b * 256 + ch) << 12);
  if (threadIdx.x < 25) wl[threadIdx.x] = lwF[ch * 25 + threadIdx.x];
  for (int idx = threadIdx.x; idx < 20 * 68; idx += 256){
    int r = idx / 68, c = idx % 68;
    int gh = h0 + r - 2, gw = c - 2;
    float v = 0.f;
    if (gh >= 0 && gh < 64 && gw >= 0 && gw < 64) v = vp[(gh << 6) + gw];
    tile[r][c] = v;
  }
  __syncthreads();
  const float bia = lbF[ch];
  #pragma unroll
  for (int r2 = 0; r2 < 4; r2++){
    int idx = threadIdx.x + r2 * 256;
    int oh = idx >> 6, ow = idx & 63;
    float s = bia;
    #pragma unroll
    for (int i = 0; i < 5; i++)
      #pragma unroll
      for (int j = 0; j < 5; j++) s += tile[oh + i][ow + j] * wl[i * 5 + j];
    Tb[(((long)b * 256 + ch) << 12) + ((h0 + oh) << 6) + ow] = s;
  }
}

// ---------------- res: Tb = (attn_res + lepe) * o ----------------
__global__ __launch_bounds__(256) void k_res(
    const float* __restrict__ Q0, const float* __restrict__ Zb,
    const float* __restrict__ KVb, const float* __restrict__ VMb,
    const float* __restrict__ Ob, float* __restrict__ Tb)
{
  int b = blockIdx.z, n = blockIdx.y;
  int l = blockIdx.x * 256 + threadIdx.x;
  const float* qp = Q0 + (((long)b * 256 + n * 32) << 12) + l;
  float q[32];
  #pragma unroll
  for (int p = 0; p < 16; p++){
    float q0 = qp[(2*p) << 12], q1 = qp[(2*p+1) << 12];
    float sn, cs; rope_sc(p, l, &sn, &cs);
    q[2*p]   = q0 * cs - q1 * sn;
    q[2*p+1] = q1 * cs + q0 * sn;
  }
  float zv = Zb[((b * 8 + n) << 12) + l];
  float f  = 1.f + 1.f / (zv + 1e-6f);
  const float* kv = KVb + (((long)b * 8 + n) << 10);
  const float* vm = VMb + b * 256 + n * 32;
  float acc[32];
  #pragma unroll
  for (int e = 0; e < 32; e++) acc[e] = 0.f;
  #pragma unroll
  for (int d = 0; d < 32; d++){
    float qd = q[d];
    #pragma unroll
    for (int e = 0; e < 32; e++) acc[e] += qd * kv[d * 32 + e];
  }
  long base = (((long)b * 256 + n * 32) << 12) + l;
  #pragma unroll
  for (int e = 0; e < 32; e++){
    float val = acc[e] * f - zv * vm[e];
    long off = base + ((long)e << 12);
    Tb[off] = (val + Tb[off]) * Ob[off];
  }
}

// ---------------- proj GEMM -> out (bf16 or fp32 per flag) ----------------
__global__ __launch_bounds__(256) void k_gemm_proj(
    const float* __restrict__ Wt,   // [256][256] fp32 (k-major)
    const float* __restrict__ T,    // [8][256][4096] fp32
    const float* __restrict__ bias, // [256] fp32
    const int* __restrict__ flag,
    void* __restrict__ out)
{
  __shared__ float As[32][68];
  __shared__ float Bs[32][68];
  const int tid = threadIdx.x;
  const int b = blockIdx.z, mt = blockIdx.y, nt = blockIdx.x;
  const int m0g = mt * 64, n0g = nt * 64;
  const int tm = tid >> 4, tn = tid & 15;

  float acc[4][4];
  #pragma unroll
  for (int i=0;i<4;i++){ acc[i][0]=0.f; acc[i][1]=0.f; acc[i][2]=0.f; acc[i][3]=0.f; }

  const float* tp = T + (((long)b * 256) << 12);

  for (int kk = 0; kk < 256; kk += 32){
    #pragma unroll
    for (int r = 0; r < 2; r++){
      int idx = tid + r * 256;
      int k = idx >> 4, mj = (idx & 15) * 4;
      *(float4*)&As[k][mj] = *(const float4*)&Wt[(kk + k) * 256 + m0g + mj];
    }
    #pragma unroll
    for (int r = 0; r < 2; r++){
      int idx = tid + r * 256;
      int k = idx >> 4, nj = (idx & 15) * 4;
      *(float4*)&Bs[k][nj] = *(const float4*)(tp + (((long)(kk + k)) << 12) + n0g + nj);
    }
    __syncthreads();
    #pragma unroll
    for (int k = 0; k < 32; k++){
      float4 av = *(float4*)&As[k][tm * 4];
      float4 bv = *(float4*)&Bs[k][tn * 4];
      float aa[4] = {av.x, av.y, av.z, av.w};
      float bb[4] = {bv.x, bv.y, bv.z, bv.w};
      #pragma unroll
      for (int i=0;i<4;i++)
        #pragma unroll
        for (int j=0;j<4;j++) acc[i][j] += aa[i] * bb[j];
    }
    __syncthreads();
  }
  const bool f32 = (*flag != 0);
  #pragma unroll
  for (int i = 0; i < 4; i++){
    int oc = m0g + tm * 4 + i;
    const float bia = bias[oc];
    long off = (((long)b * 256 + oc) << 12) + n0g + tn * 4;
    if (f32){
      float4 v;
      v.x = acc[i][0] + bia; v.y = acc[i][1] + bia;
      v.z = acc[i][2] + bia; v.w = acc[i][3] + bia;
      *(float4*)((float*)out + off) = v;
    } else {
      ushort4 o4;
      o4.x = f2bf(acc[i][0] + bia); o4.y = f2bf(acc[i][1] + bia);
      o4.z = f2bf(acc[i][2] + bia); o4.w = f2bf(acc[i][3] + bia);
      *(ushort4*)((u16*)out + off) = o4;
    }
  }
}

extern "C" void kernel_launch(void* const* d_in, const int* in_sizes, int n_in,
                              void* d_out, int out_size, void* d_ws, size_t ws_size,
                              hipStream_t stream)
{
  const void* x  = d_in[0];   // (8,256,64,64)
  const void* qw = d_in[1];   // (1024,256,1,1)
  const void* qb = d_in[2];   // (1024,)
  const void* lw = d_in[3];   // (256,1,5,5)
  const void* lb = d_in[4];   // (256,)
  const void* pw = d_in[5];   // (256,256,1,1)
  const void* pb = d_in[6];   // (256,)

  float* ws  = (float*)d_ws;
  float* Q0  = ws;                       // 8*256*4096
  float* K0  = Q0 + 8388608;
  float* Vb  = K0 + 8388608;
  float* Ob  = Vb + 8388608;
  float* Tb  = Ob + 8388608;             // doubles as Xf (x dead before lepe writes)
  float* Xf  = Tb;
  float* Zb  = Tb + 8388608;             // 8*8*4096
  float* KMb = Zb + 262144;              // 8*256
  float* VMb = KMb + 2048;
  float* KVb = VMb + 2048;               // 8*8*32*32
  float* WtA = KVb + 65536;              // 256*1024
  float* WtP = WtA + 262144;             // 256*256
  float* qbF = WtP + 65536;              // 1024
  float* lwF = qbF + 1024;               // 6400
  float* lbF = lwF + 6400;               // 256
  float* pbF = lbF + 256;                // 256
  int*  flag = (int*)(pbF + 256);        // 16 floats reserved
  // total: 42,610,448 floats ~= 170.4 MB
  if (ws_size < (size_t)42610448 * 4) return;

  hipMemsetAsync(KVb, 0, 65536 * 4, stream);
  k_detect<<<1, 256, 0, stream>>>((const u16*)qw, flag);
  k_prep<<<1024, 256, 0, stream>>>(qw, pw, qb, lw, lb, pb, flag,
                                   WtA, WtP, qbF, lwF, lbF, pbF);
  k_cvtx<<<32768, 256, 0, stream>>>(x, flag, Xf);
  k_gemm_qkvo<<<dim3(64, 16, 8), 256, 0, stream>>>(WtA, Xf, qbF, Q0, K0, Vb, Ob);
  k_means<<<dim3(256, 8, 2), 256, 0, stream>>>(K0, Vb, KMb, VMb);
  k_z<<<dim3(16, 8, 8), 256, 0, stream>>>(Q0, KMb, Zb);
  k_kv<<<dim3(8, 8, 8), 256, 0, stream>>>(K0, Vb, KVb);
  k_lepe<<<dim3(4, 256, 8), 256, 0, stream>>>(Vb, lwF, lbF, Tb);
  k_res<<<dim3(16, 8, 8), 256, 0, stream>>>(Q0, Zb, KVb, VMb, Ob, Tb);
  k_gemm_proj<<<dim3(64, 4, 8), 256, 0, stream>>>(WtP, Tb, pbF, flag, d_out);
}

// Round 3
// 356.062 us; speedup vs baseline: 1.3816x; 1.3816x over previous
//
#include <hip/hip_runtime.h>
#include <math.h>

typedef unsigned short u16;
typedef unsigned int u32;
typedef __attribute__((ext_vector_type(8))) short short8;
typedef __attribute__((ext_vector_type(4))) float f32x4;

// B=8, C=256, H=W=64, L=4096, NH=8, HD=32. Inputs/outputs fp32 (verified round 2).
static constexpr float SCALE = 0.17677669529663687f;          // 1/sqrt(32)
static constexpr float C2    = 0.17677669529663687f / 4096.f; // (scale/L) = c^2

__device__ __forceinline__ float bf2f(u16 u){
  union { u32 i; float f; } v; v.i = ((u32)u) << 16; return v.f;
}
__device__ __forceinline__ u16 f2bf(float f){
  union { float fl; u32 i; } v; v.fl = f;
  u32 r = v.i + 0x7fffu + ((v.i >> 16) & 1u);   // RNE
  return (u16)(r >> 16);
}
__device__ __forceinline__ float eluP(float x){ return x > 0.f ? x + 1.f : expf(x); }
__device__ __forceinline__ float rfreq(int j){
  const float t[8] = {1.f, 0.2682695795f, 0.0719685673f, 0.0193069773f,
                      0.0051794747f, 0.0013894955f, 0.0003727594f, 1e-4f};
  return t[j];
}
__device__ __forceinline__ void rope_sc(int p, int l, float* sn, float* cs){
  int pos = (p < 8) ? (l >> 6) : (l & 63);
  float th = rfreq(p & 7) * (float)pos;
  sincosf(th, sn, cs);
}

// ---------------- weight split: fp32 -> bf16 hi/lo, keep [m][k] ----------------
__global__ __launch_bounds__(256) void k_prep(
    const float* __restrict__ qw, const float* __restrict__ pw,
    u16* __restrict__ Whi, u16* __restrict__ Wlo,
    u16* __restrict__ Phi, u16* __restrict__ Plo)
{
  int idx = blockIdx.x * 256 + threadIdx.x;
  if (idx < 262144){
    float v = qw[idx]; u16 h = f2bf(v);
    Whi[idx] = h; Wlo[idx] = f2bf(v - bf2f(h));
  }
  if (idx < 65536){
    float v = pw[idx]; u16 h = f2bf(v);
    Phi[idx] = h; Plo[idx] = f2bf(v - bf2f(h));
  }
}

// ---------------- x [b][c][l] fp32 -> XThi/XTlo [b][l][c] bf16 ----------------
// grid (64 lb, 4 cb, 8 b), 64x64 tiles
__global__ __launch_bounds__(256) void k_xt(
    const float* __restrict__ x, u16* __restrict__ XThi, u16* __restrict__ XTlo)
{
  __shared__ float t[64][65];
  int l0 = blockIdx.x * 64, c0 = blockIdx.y * 64, b = blockIdx.z;
  const float* xp = x + (((long)b * 256 + c0) << 12) + l0;
  #pragma unroll
  for (int rep = 0; rep < 4; rep++){
    int idx = threadIdx.x + rep * 256;
    int r = idx >> 4, ch = (idx & 15) * 4;       // r = c-row, ch = l-chunk
    float4 f = *(const float4*)&xp[((long)r << 12) + ch];
    t[r][ch] = f.x; t[r][ch+1] = f.y; t[r][ch+2] = f.z; t[r][ch+3] = f.w;
  }
  __syncthreads();
  int r2 = threadIdx.x >> 2, c8 = (threadIdx.x & 3) * 16;   // r2 = l-row, c8 = c-chunk
  u32 whi[8], wlo[8];
  #pragma unroll
  for (int j = 0; j < 8; j++){
    float v0 = t[c8 + 2*j][r2], v1 = t[c8 + 2*j + 1][r2];
    u16 h0 = f2bf(v0), h1 = f2bf(v1);
    u16 l0b = f2bf(v0 - bf2f(h0)), l1b = f2bf(v1 - bf2f(h1));
    whi[j] = (u32)h0 | ((u32)h1 << 16);
    wlo[j] = (u32)l0b | ((u32)l1b << 16);
  }
  long ob = (((long)b << 12) << 8) + ((long)(l0 + r2) << 8) + c0 + c8;  // u16 index
  *(uint4*)&XThi[ob]     = make_uint4(whi[0], whi[1], whi[2], whi[3]);
  *(uint4*)&XThi[ob + 8] = make_uint4(whi[4], whi[5], whi[6], whi[7]);
  *(uint4*)&XTlo[ob]     = make_uint4(wlo[0], wlo[1], wlo[2], wlo[3]);
  *(uint4*)&XTlo[ob + 8] = make_uint4(wlo[4], wlo[5], wlo[6], wlo[7]);
}

// ---------------- split-bf16 triple-product MFMA GEMM ----------------
// C[m][n] = sum_k W[m][k] * B[k][n], W split hi/lo [M][256], B^T split hi/lo [b][4096][256]
// block 128x128, BK=32, 4 waves each 64x64, mfma 16x16x32_bf16
// MODE 0: qkvo (M=1024, outputs Q0/K0/Vb/Ob fp32 [b][c][l], eluP on q,k)
// MODE 1: proj (M=256, output d_out fp32 [b][c][l])
template<int MODE>
__global__ __launch_bounds__(256) void k_gemm3(
    const u16* __restrict__ Whi_, const u16* __restrict__ Wlo_,
    const u16* __restrict__ Bhi_, const u16* __restrict__ Blo_,
    const float* __restrict__ bias,
    float* __restrict__ O0, float* __restrict__ O1,
    float* __restrict__ O2, float* __restrict__ O3)
{
  __shared__ __align__(16) u16 Ah[128 * 40];   // pitch 40 u16 = 80 B (20 banks)
  __shared__ __align__(16) u16 Al[128 * 40];
  __shared__ __align__(16) u16 Bh[128 * 40];
  __shared__ __align__(16) u16 Bl[128 * 40];
  const int tid = threadIdx.x;
  const int nt = blockIdx.x, mt = blockIdx.y, b = blockIdx.z;
  const int m0 = mt * 128, n0 = nt * 128;
  const int wave = tid >> 6, lane = tid & 63;
  const int wm = wave & 1, wn = wave >> 1, qu = lane >> 4, ln = lane & 15;

  const long bOff = ((long)b << 12) << 8;      // b*4096*256
  const u16* bhp = Bhi_ + bOff;
  const u16* blp = Blo_ + bOff;

  f32x4 acc[4][4];
  #pragma unroll
  for (int im = 0; im < 4; im++)
    #pragma unroll
    for (int in = 0; in < 4; in++)
      #pragma unroll
      for (int r = 0; r < 4; r++) acc[im][in][r] = 0.f;

  for (int kk = 0; kk < 256; kk += 32){
    #pragma unroll
    for (int rep = 0; rep < 2; rep++){
      int r = (tid >> 2) + rep * 64;
      int c = (tid & 3) * 8;
      int ga = (m0 + r) * 256 + kk + c;
      long gb = (long)(n0 + r) * 256 + kk + c;
      *(short8*)&Ah[r * 40 + c] = *(const short8*)&Whi_[ga];
      *(short8*)&Al[r * 40 + c] = *(const short8*)&Wlo_[ga];
      *(short8*)&Bh[r * 40 + c] = *(const short8*)&bhp[gb];
      *(short8*)&Bl[r * 40 + c] = *(const short8*)&blp[gb];
    }
    __syncthreads();
    short8 fbh[4], fbl[4];
    #pragma unroll
    for (int in = 0; in < 4; in++){
      int row = wn * 64 + in * 16 + ln;
      fbh[in] = *(short8*)&Bh[row * 40 + qu * 8];
      fbl[in] = *(short8*)&Bl[row * 40 + qu * 8];
    }
    #pragma unroll
    for (int im = 0; im < 4; im++){
      int row = wm * 64 + im * 16 + ln;
      short8 fah = *(short8*)&Ah[row * 40 + qu * 8];
      short8 fal = *(short8*)&Al[row * 40 + qu * 8];
      #pragma unroll
      for (int in = 0; in < 4; in++){
        acc[im][in] = __builtin_amdgcn_mfma_f32_16x16x32_bf16(fah, fbh[in], acc[im][in], 0, 0, 0);
        acc[im][in] = __builtin_amdgcn_mfma_f32_16x16x32_bf16(fah, fbl[in], acc[im][in], 0, 0, 0);
        acc[im][in] = __builtin_amdgcn_mfma_f32_16x16x32_bf16(fal, fbh[in], acc[im][in], 0, 0, 0);
      }
    }
    __syncthreads();
  }

  // epilogue: C/D layout col = lane&15 (n), row = quad*4 + reg (m)
  if (MODE == 0){
    const int range = m0 >> 8;                 // 0:q 1:k 2:v 3:o (block-uniform)
    float* dst = (range == 0) ? O0 : (range == 1) ? O1 : (range == 2) ? O2 : O3;
    #pragma unroll
    for (int im = 0; im < 4; im++){
      int mbase = m0 + wm * 64 + im * 16 + qu * 4;
      #pragma unroll
      for (int r = 0; r < 4; r++){
        int m = mbase + r;
        float bia = bias[m];
        float* row = dst + (((long)b * 256 + (m & 255)) << 12);
        #pragma unroll
        for (int in = 0; in < 4; in++){
          int n = n0 + wn * 64 + in * 16 + ln;
          float v = acc[im][in][r] + bia;
          if (range < 2) v = eluP(v);
          row[n] = v;
        }
      }
    }
  } else {
    #pragma unroll
    for (int im = 0; im < 4; im++){
      int mbase = m0 + wm * 64 + im * 16 + qu * 4;
      #pragma unroll
      for (int r = 0; r < 4; r++){
        int m = mbase + r;
        float bia = bias[m];
        float* row = O0 + (((long)b * 256 + m) << 12);
        #pragma unroll
        for (int in = 0; in < 4; in++){
          int n = n0 + wn * 64 + in * 16 + ln;
          row[n] = acc[im][in][r] + bia;
        }
      }
    }
  }
}

// ---------------- channel means over L ----------------
__global__ __launch_bounds__(256) void k_means(
    const float* __restrict__ K0, const float* __restrict__ Vb,
    float* __restrict__ KMb, float* __restrict__ VMb)
{
  int ch = blockIdx.x, b = blockIdx.y, which = blockIdx.z;
  const float* src = (which ? Vb : K0) + (((long)b * 256 + ch) << 12);
  float s = 0.f;
  for (int i = threadIdx.x; i < 4096; i += 256) s += src[i];
  #pragma unroll
  for (int off = 32; off > 0; off >>= 1) s += __shfl_down(s, off);
  __shared__ float red[4];
  if ((threadIdx.x & 63) == 0) red[threadIdx.x >> 6] = s;
  __syncthreads();
  if (threadIdx.x == 0)
    (which ? VMb : KMb)[b * 256 + ch] = (red[0]+red[1]+red[2]+red[3]) * (1.f/4096.f);
}

// ---------------- kv[b,n,d,e] = c2 * sum_l ropeK[d][l] * V[e][l] ----------------
__global__ __launch_bounds__(256) void k_kv(
    const float* __restrict__ K0, const float* __restrict__ Vb, float* __restrict__ KVb)
{
  __shared__ float Kl[32][65];
  __shared__ float Vl[32][65];
  int b = blockIdx.z, n = blockIdx.y, ls = blockIdx.x;
  int tid = threadIdx.x;
  const float* kp = K0 + (((long)b * 256 + n * 32) << 12);
  const float* vp = Vb + (((long)b * 256 + n * 32) << 12);
  int lane = tid & 63, grp = tid >> 6;
  int eg = tid & 15, dg = tid >> 4;
  float a00=0.f, a01=0.f, a10=0.f, a11=0.f;

  for (int l0 = ls * 512; l0 < ls * 512 + 512; l0 += 64){
    int lg = l0 + lane;
    #pragma unroll
    for (int r = 0; r < 4; r++){
      int p = grp + (r << 2);
      float k0 = kp[((2*p) << 12) + lg];
      float k1 = kp[((2*p+1) << 12) + lg];
      float sn, cs; rope_sc(p, lg, &sn, &cs);
      Kl[2*p][lane]   = k0 * cs - k1 * sn;
      Kl[2*p+1][lane] = k1 * cs + k0 * sn;
    }
    #pragma unroll
    for (int r = 0; r < 8; r++){
      int ch = grp + (r << 2);
      Vl[ch][lane] = vp[(ch << 12) + lg];
    }
    __syncthreads();
    #pragma unroll
    for (int l = 0; l < 64; l++){
      float v0 = Vl[eg][l], v1 = Vl[eg + 16][l];
      float kA = Kl[dg][l], kB = Kl[dg + 16][l];
      a00 += kA * v0; a01 += kA * v1;
      a10 += kB * v0; a11 += kB * v1;
    }
    __syncthreads();
  }
  float* dst = KVb + (((long)b * 8 + n) << 10);
  atomicAdd(&dst[dg * 32 + eg],             a00 * C2);
  atomicAdd(&dst[dg * 32 + eg + 16],        a01 * C2);
  atomicAdd(&dst[(dg + 16) * 32 + eg],      a10 * C2);
  atomicAdd(&dst[(dg + 16) * 32 + eg + 16], a11 * C2);
}

// ---------------- lepe = depthwise 5x5 (pad 2) of V -> Tb ----------------
__global__ __launch_bounds__(256) void k_lepe(
    const float* __restrict__ Vb, const float* __restrict__ lw,
    const float* __restrict__ lb, float* __restrict__ Tb)
{
  __shared__ float tile[20][68];
  __shared__ float wl[25];
  int ht = blockIdx.x, ch = blockIdx.y, b = blockIdx.z;
  int h0 = ht * 16;
  const float* vp = Vb + (((long)b * 256 + ch) << 12);
  if (threadIdx.x < 25) wl[threadIdx.x] = lw[ch * 25 + threadIdx.x];
  for (int idx = threadIdx.x; idx < 20 * 68; idx += 256){
    int r = idx / 68, c = idx % 68;
    int gh = h0 + r - 2, gw = c - 2;
    float v = 0.f;
    if (gh >= 0 && gh < 64 && gw >= 0 && gw < 64) v = vp[(gh << 6) + gw];
    tile[r][c] = v;
  }
  __syncthreads();
  const float bia = lb[ch];
  #pragma unroll
  for (int r2 = 0; r2 < 4; r2++){
    int idx = threadIdx.x + r2 * 256;
    int oh = idx >> 6, ow = idx & 63;
    float s = bia;
    #pragma unroll
    for (int i = 0; i < 5; i++)
      #pragma unroll
      for (int j = 0; j < 5; j++) s += tile[oh + i][ow + j] * wl[i * 5 + j];
    Tb[(((long)b * 256 + ch) << 12) + ((h0 + oh) << 6) + ow] = s;
  }
}

// ---------------- res (+fused z): TT^T hi/lo = ((q.kv)*f - z*vm + lepe) * o ----------------
__global__ __launch_bounds__(256) void k_res(
    const float* __restrict__ Q0, const float* __restrict__ KMb,
    const float* __restrict__ KVb, const float* __restrict__ VMb,
    const float* __restrict__ Ob, const float* __restrict__ Tb,
    u16* __restrict__ TThi, u16* __restrict__ TTlo)
{
  int b = blockIdx.z, n = blockIdx.y;
  int l = blockIdx.x * 256 + threadIdx.x;
  const float* qp = Q0 + (((long)b * 256 + n * 32) << 12) + l;
  const float* km = KMb + b * 256 + n * 32;
  float q0v[32];
  #pragma unroll
  for (int d = 0; d < 32; d++) q0v[d] = qp[(long)d << 12];
  float z = 0.f;
  #pragma unroll
  for (int d = 0; d < 32; d++) z += q0v[d] * km[d];
  z *= SCALE;
  float q[32];
  #pragma unroll
  for (int p = 0; p < 16; p++){
    float sn, cs; rope_sc(p, l, &sn, &cs);
    q[2*p]   = q0v[2*p] * cs - q0v[2*p+1] * sn;
    q[2*p+1] = q0v[2*p+1] * cs + q0v[2*p] * sn;
  }
  float f = 1.f + 1.f / (z + 1e-6f);
  const float* kv = KVb + (((long)b * 8 + n) << 10);
  const float* vm = VMb + b * 256 + n * 32;
  float acc[32];
  #pragma unroll
  for (int e = 0; e < 32; e++) acc[e] = 0.f;
  #pragma unroll
  for (int d = 0; d < 32; d++){
    float qd = q[d];
    #pragma unroll
    for (int e = 0; e < 32; e++) acc[e] += qd * kv[d * 32 + e];
  }
  long base = (((long)b * 256 + n * 32) << 12) + l;
  u32 whi[16], wlo[16];
  #pragma unroll
  for (int e = 0; e < 32; e++){
    long off = base + ((long)e << 12);
    float val = (acc[e] * f - z * vm[e] + Tb[off]) * Ob[off];
    u16 h = f2bf(val), lo16 = f2bf(val - bf2f(h));
    if (e & 1){ whi[e >> 1] |= ((u32)h << 16); wlo[e >> 1] |= ((u32)lo16 << 16); }
    else      { whi[e >> 1] = h;               wlo[e >> 1] = lo16; }
  }
  long ob = (((long)b << 12) << 8) + ((long)l << 8) + n * 32;  // u16 index [b][l][c]
  #pragma unroll
  for (int j = 0; j < 4; j++){
    *(uint4*)&TThi[ob + j * 8] = make_uint4(whi[4*j], whi[4*j+1], whi[4*j+2], whi[4*j+3]);
    *(uint4*)&TTlo[ob + j * 8] = make_uint4(wlo[4*j], wlo[4*j+1], wlo[4*j+2], wlo[4*j+3]);
  }
}

extern "C" void kernel_launch(void* const* d_in, const int* in_sizes, int n_in,
                              void* d_out, int out_size, void* d_ws, size_t ws_size,
                              hipStream_t stream)
{
  const float* x  = (const float*)d_in[0];   // (8,256,64,64) fp32
  const float* qw = (const float*)d_in[1];   // (1024,256,1,1)
  const float* qb = (const float*)d_in[2];   // (1024,)
  const float* lw = (const float*)d_in[3];   // (256,1,5,5)
  const float* lb = (const float*)d_in[4];   // (256,)
  const float* pw = (const float*)d_in[5];   // (256,256,1,1)
  const float* pb = (const float*)d_in[6];   // (256,)

  float* ws  = (float*)d_ws;
  float* Q0  = ws;                        // 8*256*4096 fp32
  float* K0  = Q0 + 8388608;              // also reused as Tb (lepe out) after k_kv
  float* Vb  = K0 + 8388608;
  float* Ob  = Vb + 8388608;
  u16*  XThi = (u16*)(Ob + 8388608);      // 8*4096*256 bf16; reused as TThi after qkvo
  u16*  XTlo = XThi + 8388608;
  u16*  Whi  = XTlo + 8388608;            // 1024*256 bf16
  u16*  Wlo  = Whi + 262144;
  u16*  Phi  = Wlo + 262144;              // 256*256 bf16
  u16*  Plo  = Phi + 65536;
  float* KMb = (float*)(Plo + 65536);     // 8*256
  float* VMb = KMb + 2048;
  float* KVb = VMb + 2048;                // 8*8*32*32
  // end: KVb + 65536 floats
  size_t total_f = 8388608ull*4 + (8388608ull*2 + 262144*2 + 65536*2)/2 + 2048 + 2048 + 65536;
  if (ws_size < total_f * 4) return;

  float* Tb = K0;          // lepe output overlays K0 (K0 dead after k_kv)
  u16* TThi = XThi;        // proj B-operand overlays XT (dead after qkvo GEMM)
  u16* TTlo = XTlo;

  hipMemsetAsync(KVb, 0, 65536 * 4, stream);
  k_prep<<<1024, 256, 0, stream>>>(qw, pw, Whi, Wlo, Phi, Plo);
  k_xt<<<dim3(64, 4, 8), 256, 0, stream>>>(x, XThi, XTlo);
  k_gemm3<0><<<dim3(32, 8, 8), 256, 0, stream>>>(Whi, Wlo, XThi, XTlo, qb, Q0, K0, Vb, Ob);
  k_means<<<dim3(256, 8, 2), 256, 0, stream>>>(K0, Vb, KMb, VMb);
  k_kv<<<dim3(8, 8, 8), 256, 0, stream>>>(K0, Vb, KVb);
  k_lepe<<<dim3(4, 256, 8), 256, 0, stream>>>(Vb, lw, lb, Tb);
  k_res<<<dim3(16, 8, 8), 256, 0, stream>>>(Q0, KMb, KVb, VMb, Ob, Tb, TThi, TTlo);
  k_gemm3<1><<<dim3(32, 2, 8), 256, 0, stream>>>(Phi, Plo, TThi, TTlo, pb,
                                                 (float*)d_out, nullptr, nullptr, nullptr);
}

// Round 4
// 310.838 us; speedup vs baseline: 1.5826x; 1.1455x over previous
//
#include <hip/hip_runtime.h>
#include <math.h>

typedef unsigned short u16;
typedef unsigned int u32;
typedef __attribute__((ext_vector_type(8))) short short8;
typedef __attribute__((ext_vector_type(4))) float f32x4;

// B=8, C=256, H=W=64, L=4096, NH=8, HD=32. Inputs/outputs fp32 (verified round 2).
static constexpr float SCALE = 0.17677669529663687f;          // 1/sqrt(32)
static constexpr float C2    = 0.17677669529663687f / 4096.f; // (scale/L) = c^2

__device__ __forceinline__ float bf2f(u16 u){
  union { u32 i; float f; } v; v.i = ((u32)u) << 16; return v.f;
}
__device__ __forceinline__ u16 f2bf(float f){
  union { float fl; u32 i; } v; v.fl = f;
  u32 r = v.i + 0x7fffu + ((v.i >> 16) & 1u);   // RNE
  return (u16)(r >> 16);
}
__device__ __forceinline__ float eluP(float x){ return x > 0.f ? x + 1.f : expf(x); }
__device__ __forceinline__ float rfreq(int j){
  const float t[8] = {1.f, 0.2682695795f, 0.0719685673f, 0.0193069773f,
                      0.0051794747f, 0.0013894955f, 0.0003727594f, 1e-4f};
  return t[j];
}

// ---------------- weight split: fp32 -> bf16 hi/lo, keep [m][k] ----------------
__global__ __launch_bounds__(256) void k_prep(
    const float* __restrict__ qw, const float* __restrict__ pw,
    u16* __restrict__ Whi, u16* __restrict__ Wlo,
    u16* __restrict__ Phi, u16* __restrict__ Plo)
{
  int idx = blockIdx.x * 256 + threadIdx.x;
  if (idx < 262144){
    float v = qw[idx]; u16 h = f2bf(v);
    Whi[idx] = h; Wlo[idx] = f2bf(v - bf2f(h));
  }
  if (idx < 65536){
    float v = pw[idx]; u16 h = f2bf(v);
    Phi[idx] = h; Plo[idx] = f2bf(v - bf2f(h));
  }
}

// ---------------- x [b][c][l] fp32 -> XThi/XTlo [b][l][c] bf16 ----------------
__global__ __launch_bounds__(256) void k_xt(
    const float* __restrict__ x, u16* __restrict__ XThi, u16* __restrict__ XTlo)
{
  __shared__ float t[64][65];
  int l0 = blockIdx.x * 64, c0 = blockIdx.y * 64, b = blockIdx.z;
  const float* xp = x + (((long)b * 256 + c0) << 12) + l0;
  #pragma unroll
  for (int rep = 0; rep < 4; rep++){
    int idx = threadIdx.x + rep * 256;
    int r = idx >> 4, ch = (idx & 15) * 4;
    float4 f = *(const float4*)&xp[((long)r << 12) + ch];
    t[r][ch] = f.x; t[r][ch+1] = f.y; t[r][ch+2] = f.z; t[r][ch+3] = f.w;
  }
  __syncthreads();
  int r2 = threadIdx.x >> 2, c8 = (threadIdx.x & 3) * 16;
  u32 whi[8], wlo[8];
  #pragma unroll
  for (int j = 0; j < 8; j++){
    float v0 = t[c8 + 2*j][r2], v1 = t[c8 + 2*j + 1][r2];
    u16 h0 = f2bf(v0), h1 = f2bf(v1);
    u16 l0b = f2bf(v0 - bf2f(h0)), l1b = f2bf(v1 - bf2f(h1));
    whi[j] = (u32)h0 | ((u32)h1 << 16);
    wlo[j] = (u32)l0b | ((u32)l1b << 16);
  }
  long ob = (((long)b << 12) << 8) + ((long)(l0 + r2) << 8) + c0 + c8;
  *(uint4*)&XThi[ob]     = make_uint4(whi[0], whi[1], whi[2], whi[3]);
  *(uint4*)&XThi[ob + 8] = make_uint4(whi[4], whi[5], whi[6], whi[7]);
  *(uint4*)&XTlo[ob]     = make_uint4(wlo[0], wlo[1], wlo[2], wlo[3]);
  *(uint4*)&XTlo[ob + 8] = make_uint4(wlo[4], wlo[5], wlo[6], wlo[7]);
}

// ---------------- split-bf16 triple-product MFMA GEMM (unchanged from r3) ----------------
template<int MODE>
__global__ __launch_bounds__(256) void k_gemm3(
    const u16* __restrict__ Whi_, const u16* __restrict__ Wlo_,
    const u16* __restrict__ Bhi_, const u16* __restrict__ Blo_,
    const float* __restrict__ bias,
    float* __restrict__ O0, float* __restrict__ O1,
    float* __restrict__ O2, float* __restrict__ O3)
{
  __shared__ __align__(16) u16 Ah[128 * 40];
  __shared__ __align__(16) u16 Al[128 * 40];
  __shared__ __align__(16) u16 Bh[128 * 40];
  __shared__ __align__(16) u16 Bl[128 * 40];
  const int tid = threadIdx.x;
  const int nt = blockIdx.x, mt = blockIdx.y, b = blockIdx.z;
  const int m0 = mt * 128, n0 = nt * 128;
  const int wave = tid >> 6, lane = tid & 63;
  const int wm = wave & 1, wn = wave >> 1, qu = lane >> 4, ln = lane & 15;

  const long bOff = ((long)b << 12) << 8;
  const u16* bhp = Bhi_ + bOff;
  const u16* blp = Blo_ + bOff;

  f32x4 acc[4][4];
  #pragma unroll
  for (int im = 0; im < 4; im++)
    #pragma unroll
    for (int in = 0; in < 4; in++)
      #pragma unroll
      for (int r = 0; r < 4; r++) acc[im][in][r] = 0.f;

  for (int kk = 0; kk < 256; kk += 32){
    #pragma unroll
    for (int rep = 0; rep < 2; rep++){
      int r = (tid >> 2) + rep * 64;
      int c = (tid & 3) * 8;
      int ga = (m0 + r) * 256 + kk + c;
      long gb = (long)(n0 + r) * 256 + kk + c;
      *(short8*)&Ah[r * 40 + c] = *(const short8*)&Whi_[ga];
      *(short8*)&Al[r * 40 + c] = *(const short8*)&Wlo_[ga];
      *(short8*)&Bh[r * 40 + c] = *(const short8*)&bhp[gb];
      *(short8*)&Bl[r * 40 + c] = *(const short8*)&blp[gb];
    }
    __syncthreads();
    short8 fbh[4], fbl[4];
    #pragma unroll
    for (int in = 0; in < 4; in++){
      int row = wn * 64 + in * 16 + ln;
      fbh[in] = *(short8*)&Bh[row * 40 + qu * 8];
      fbl[in] = *(short8*)&Bl[row * 40 + qu * 8];
    }
    #pragma unroll
    for (int im = 0; im < 4; im++){
      int row = wm * 64 + im * 16 + ln;
      short8 fah = *(short8*)&Ah[row * 40 + qu * 8];
      short8 fal = *(short8*)&Al[row * 40 + qu * 8];
      #pragma unroll
      for (int in = 0; in < 4; in++){
        acc[im][in] = __builtin_amdgcn_mfma_f32_16x16x32_bf16(fah, fbh[in], acc[im][in], 0, 0, 0);
        acc[im][in] = __builtin_amdgcn_mfma_f32_16x16x32_bf16(fah, fbl[in], acc[im][in], 0, 0, 0);
        acc[im][in] = __builtin_amdgcn_mfma_f32_16x16x32_bf16(fal, fbh[in], acc[im][in], 0, 0, 0);
      }
    }
    __syncthreads();
  }

  if (MODE == 0){
    const int range = m0 >> 8;
    float* dst = (range == 0) ? O0 : (range == 1) ? O1 : (range == 2) ? O2 : O3;
    #pragma unroll
    for (int im = 0; im < 4; im++){
      int mbase = m0 + wm * 64 + im * 16 + qu * 4;
      #pragma unroll
      for (int r = 0; r < 4; r++){
        int m = mbase + r;
        float bia = bias[m];
        float* row = dst + (((long)b * 256 + (m & 255)) << 12);
        #pragma unroll
        for (int in = 0; in < 4; in++){
          int n = n0 + wn * 64 + in * 16 + ln;
          float v = acc[im][in][r] + bia;
          if (range < 2) v = eluP(v);
          row[n] = v;
        }
      }
    }
  } else {
    #pragma unroll
    for (int im = 0; im < 4; im++){
      int mbase = m0 + wm * 64 + im * 16 + qu * 4;
      #pragma unroll
      for (int r = 0; r < 4; r++){
        int m = mbase + r;
        float bia = bias[m];
        float* row = O0 + (((long)b * 256 + m) << 12);
        #pragma unroll
        for (int in = 0; in < 4; in++){
          int n = n0 + wn * 64 + in * 16 + ln;
          row[n] = acc[im][in][r] + bia;
        }
      }
    }
  }
}

// ---------------- channel means over L ----------------
__global__ __launch_bounds__(256) void k_means(
    const float* __restrict__ K0, const float* __restrict__ Vb,
    float* __restrict__ KMb, float* __restrict__ VMb)
{
  int ch = blockIdx.x, b = blockIdx.y, which = blockIdx.z;
  const float* src = (which ? Vb : K0) + (((long)b * 256 + ch) << 12);
  float s = 0.f;
  for (int i = threadIdx.x; i < 4096; i += 256) s += src[i];
  #pragma unroll
  for (int off = 32; off > 0; off >>= 1) s += __shfl_down(s, off);
  __shared__ float red[4];
  if ((threadIdx.x & 63) == 0) red[threadIdx.x >> 6] = s;
  __syncthreads();
  if (threadIdx.x == 0)
    (which ? VMb : KMb)[b * 256 + ch] = (red[0]+red[1]+red[2]+red[3]) * (1.f/4096.f);
}

// ---------------- kv[b,n,d,e] = c2 * sum_l ropeK[d][l] * V[e][l] ----------------
// LDS rope table replaces 32 sincosf/thread with 2
__global__ __launch_bounds__(256) void k_kv(
    const float* __restrict__ K0, const float* __restrict__ Vb, float* __restrict__ KVb)
{
  __shared__ float Kl[32][65];
  __shared__ float Vl[32][65];
  __shared__ float scs[2][8][64];   // [sin/cos][freq][pos]
  int b = blockIdx.z, n = blockIdx.y, ls = blockIdx.x;
  int tid = threadIdx.x;
  #pragma unroll
  for (int r = 0; r < 2; r++){
    int idx = tid + r * 256;
    int jj = idx >> 6, pp = idx & 63;
    float sn, cs; sincosf(rfreq(jj) * (float)pp, &sn, &cs);
    scs[0][jj][pp] = sn; scs[1][jj][pp] = cs;
  }
  __syncthreads();
  const float* kp = K0 + (((long)b * 256 + n * 32) << 12);
  const float* vp = Vb + (((long)b * 256 + n * 32) << 12);
  int lane = tid & 63, grp = tid >> 6;
  int eg = tid & 15, dg = tid >> 4;
  float a00=0.f, a01=0.f, a10=0.f, a11=0.f;

  for (int l0 = ls * 512; l0 < ls * 512 + 512; l0 += 64){
    int lg = l0 + lane;
    #pragma unroll
    for (int r = 0; r < 4; r++){
      int p = grp + (r << 2);
      float k0 = kp[((2*p) << 12) + lg];
      float k1 = kp[((2*p+1) << 12) + lg];
      int pos = (p < 8) ? (lg >> 6) : (lg & 63);
      float sn = scs[0][p & 7][pos], cs = scs[1][p & 7][pos];
      Kl[2*p][lane]   = k0 * cs - k1 * sn;
      Kl[2*p+1][lane] = k1 * cs + k0 * sn;
    }
    #pragma unroll
    for (int r = 0; r < 8; r++){
      int ch = grp + (r << 2);
      Vl[ch][lane] = vp[(ch << 12) + lg];
    }
    __syncthreads();
    #pragma unroll
    for (int l = 0; l < 64; l++){
      float v0 = Vl[eg][l], v1 = Vl[eg + 16][l];
      float kA = Kl[dg][l], kB = Kl[dg + 16][l];
      a00 += kA * v0; a01 += kA * v1;
      a10 += kB * v0; a11 += kB * v1;
    }
    __syncthreads();
  }
  float* dst = KVb + (((long)b * 8 + n) << 10);
  atomicAdd(&dst[dg * 32 + eg],             a00 * C2);
  atomicAdd(&dst[dg * 32 + eg + 16],        a01 * C2);
  atomicAdd(&dst[(dg + 16) * 32 + eg],      a10 * C2);
  atomicAdd(&dst[(dg + 16) * 32 + eg + 16], a11 * C2);
}

// ---------------- lepe = depthwise 5x5 (pad 2) of V -> Tb ----------------
__global__ __launch_bounds__(256) void k_lepe(
    const float* __restrict__ Vb, const float* __restrict__ lw,
    const float* __restrict__ lb, float* __restrict__ Tb)
{
  __shared__ float tile[20][68];
  __shared__ float wl[25];
  int ht = blockIdx.x, ch = blockIdx.y, b = blockIdx.z;
  int h0 = ht * 16;
  const float* vp = Vb + (((long)b * 256 + ch) << 12);
  if (threadIdx.x < 25) wl[threadIdx.x] = lw[ch * 25 + threadIdx.x];
  for (int idx = threadIdx.x; idx < 20 * 68; idx += 256){
    int r = idx / 68, c = idx % 68;
    int gh = h0 + r - 2, gw = c - 2;
    float v = 0.f;
    if (gh >= 0 && gh < 64 && gw >= 0 && gw < 64) v = vp[(gh << 6) + gw];
    tile[r][c] = v;
  }
  __syncthreads();
  const float bia = lb[ch];
  #pragma unroll
  for (int r2 = 0; r2 < 4; r2++){
    int idx = threadIdx.x + r2 * 256;
    int oh = idx >> 6, ow = idx & 63;
    float s = bia;
    #pragma unroll
    for (int i = 0; i < 5; i++)
      #pragma unroll
      for (int j = 0; j < 5; j++) s += tile[oh + i][ow + j] * wl[i * 5 + j];
    Tb[(((long)b * 256 + ch) << 12) + ((h0 + oh) << 6) + ow] = s;
  }
}

// ---------------- res (+fused z): kv in LDS, rope table, 2 l per thread ----------------
// grid (8 lt, 8 n, 8 b), 256 thr; each thread handles l0+tid and l0+tid+256
__global__ __launch_bounds__(256) void k_res(
    const float* __restrict__ Q0, const float* __restrict__ KMb,
    const float* __restrict__ KVb, const float* __restrict__ VMb,
    const float* __restrict__ Ob, const float* __restrict__ Tb,
    u16* __restrict__ TThi, u16* __restrict__ TTlo)
{
  __shared__ __align__(16) float kvs[1024];
  __shared__ float scs[2][8][64];
  __shared__ float kms[32], vms[32];
  const int b = blockIdx.z, n = blockIdx.y, tid = threadIdx.x;
  #pragma unroll
  for (int r = 0; r < 2; r++){
    int idx = tid + r * 256;
    int jj = idx >> 6, pp = idx & 63;
    float sn, cs; sincosf(rfreq(jj) * (float)pp, &sn, &cs);
    scs[0][jj][pp] = sn; scs[1][jj][pp] = cs;
  }
  {
    const float* kv = KVb + (((long)b * 8 + n) << 10);
    #pragma unroll
    for (int r = 0; r < 4; r++) kvs[tid + r * 256] = kv[tid + r * 256];
    if (tid < 32){
      kms[tid] = KMb[b * 256 + n * 32 + tid];
      vms[tid] = VMb[b * 256 + n * 32 + tid];
    }
  }
  __syncthreads();

  const int l0 = blockIdx.x * 512;
  const int la = l0 + tid, lb_ = l0 + tid + 256;
  const float* qp = Q0 + (((long)b * 256 + n * 32) << 12);

  float q[2][32];
  #pragma unroll
  for (int d = 0; d < 32; d++){
    q[0][d] = qp[((long)d << 12) + la];
    q[1][d] = qp[((long)d << 12) + lb_];
  }
  float z[2] = {0.f, 0.f};
  #pragma unroll
  for (int d = 0; d < 32; d++){
    z[0] += q[0][d] * kms[d];
    z[1] += q[1][d] * kms[d];
  }
  z[0] *= SCALE; z[1] *= SCALE;
  // rope in place
  #pragma unroll
  for (int t = 0; t < 2; t++){
    int l = t ? lb_ : la;
    #pragma unroll
    for (int p = 0; p < 16; p++){
      int pos = (p < 8) ? (l >> 6) : (l & 63);
      float sn = scs[0][p & 7][pos], cs = scs[1][p & 7][pos];
      float q0 = q[t][2*p], q1 = q[t][2*p+1];
      q[t][2*p]   = q0 * cs - q1 * sn;
      q[t][2*p+1] = q1 * cs + q0 * sn;
    }
  }

  float acc0[32], acc1[32];
  #pragma unroll
  for (int e = 0; e < 32; e++){ acc0[e] = 0.f; acc1[e] = 0.f; }
  #pragma unroll 8
  for (int d = 0; d < 32; d++){
    float q0d = q[0][d], q1d = q[1][d];
    #pragma unroll
    for (int ec = 0; ec < 8; ec++){
      float4 kvv = *(float4*)&kvs[d * 32 + ec * 4];
      acc0[ec*4+0] += q0d * kvv.x; acc1[ec*4+0] += q1d * kvv.x;
      acc0[ec*4+1] += q0d * kvv.y; acc1[ec*4+1] += q1d * kvv.y;
      acc0[ec*4+2] += q0d * kvv.z; acc1[ec*4+2] += q1d * kvv.z;
      acc0[ec*4+3] += q0d * kvv.w; acc1[ec*4+3] += q1d * kvv.w;
    }
  }

  const float f0 = 1.f + 1.f / (z[0] + 1e-6f);
  const float f1 = 1.f + 1.f / (z[1] + 1e-6f);
  const long base = (((long)b * 256 + n * 32) << 12);
  #pragma unroll
  for (int t = 0; t < 2; t++){
    int l = t ? lb_ : la;
    float f = t ? f1 : f0, zv = t ? z[1] : z[0];
    float* accp = t ? acc1 : acc0;
    u32 whi[16], wlo[16];
    #pragma unroll
    for (int e = 0; e < 32; e++){
      long off = base + ((long)e << 12) + l;
      float val = (accp[e] * f - zv * vms[e] + Tb[off]) * Ob[off];
      u16 h = f2bf(val), lo16 = f2bf(val - bf2f(h));
      if (e & 1){ whi[e >> 1] |= ((u32)h << 16); wlo[e >> 1] |= ((u32)lo16 << 16); }
      else      { whi[e >> 1] = h;               wlo[e >> 1] = lo16; }
    }
    long ob = (((long)b << 12) << 8) + ((long)l << 8) + n * 32;
    #pragma unroll
    for (int j = 0; j < 4; j++){
      *(uint4*)&TThi[ob + j * 8] = make_uint4(whi[4*j], whi[4*j+1], whi[4*j+2], whi[4*j+3]);
      *(uint4*)&TTlo[ob + j * 8] = make_uint4(wlo[4*j], wlo[4*j+1], wlo[4*j+2], wlo[4*j+3]);
    }
  }
}

extern "C" void kernel_launch(void* const* d_in, const int* in_sizes, int n_in,
                              void* d_out, int out_size, void* d_ws, size_t ws_size,
                              hipStream_t stream)
{
  const float* x  = (const float*)d_in[0];
  const float* qw = (const float*)d_in[1];
  const float* qb = (const float*)d_in[2];
  const float* lw = (const float*)d_in[3];
  const float* lb = (const float*)d_in[4];
  const float* pw = (const float*)d_in[5];
  const float* pb = (const float*)d_in[6];

  float* ws  = (float*)d_ws;
  float* Q0  = ws;                        // 8*256*4096 fp32
  float* K0  = Q0 + 8388608;              // reused as Tb (lepe out) after k_kv
  float* Vb  = K0 + 8388608;
  float* Ob  = Vb + 8388608;
  u16*  XThi = (u16*)(Ob + 8388608);      // 8*4096*256 bf16; reused as TThi
  u16*  XTlo = XThi + 8388608;
  u16*  Whi  = XTlo + 8388608;
  u16*  Wlo  = Whi + 262144;
  u16*  Phi  = Wlo + 262144;
  u16*  Plo  = Phi + 65536;
  float* KMb = (float*)(Plo + 65536);
  float* VMb = KMb + 2048;
  float* KVb = VMb + 2048;
  size_t total_f = 8388608ull*4 + (8388608ull*2 + 262144*2 + 65536*2)/2 + 2048 + 2048 + 65536;
  if (ws_size < total_f * 4) return;

  float* Tb = K0;
  u16* TThi = XThi;
  u16* TTlo = XTlo;

  hipMemsetAsync(KVb, 0, 65536 * 4, stream);
  k_prep<<<1024, 256, 0, stream>>>(qw, pw, Whi, Wlo, Phi, Plo);
  k_xt<<<dim3(64, 4, 8), 256, 0, stream>>>(x, XThi, XTlo);
  k_gemm3<0><<<dim3(32, 8, 8), 256, 0, stream>>>(Whi, Wlo, XThi, XTlo, qb, Q0, K0, Vb, Ob);
  k_means<<<dim3(256, 8, 2), 256, 0, stream>>>(K0, Vb, KMb, VMb);
  k_kv<<<dim3(8, 8, 8), 256, 0, stream>>>(K0, Vb, KVb);
  k_lepe<<<dim3(4, 256, 8), 256, 0, stream>>>(Vb, lw, lb, Tb);
  k_res<<<dim3(8, 8, 8), 256, 0, stream>>>(Q0, KMb, KVb, VMb, Ob, Tb, TThi, TTlo);
  k_gemm3<1><<<dim3(32, 2, 8), 256, 0, stream>>>(Phi, Plo, TThi, TTlo, pb,
                                                 (float*)d_out, nullptr, nullptr, nullptr);
}

// Round 5
// 276.788 us; speedup vs baseline: 1.7773x; 1.1230x over previous
//
#include <hip/hip_runtime.h>
#include <math.h>

typedef unsigned short u16;
typedef unsigned int u32;
typedef __attribute__((ext_vector_type(8))) short short8;
typedef __attribute__((ext_vector_type(4))) float f32x4;
typedef __attribute__((ext_vector_type(16))) float f32x16;

// B=8, C=256, H=W=64, L=4096, NH=8, HD=32. Inputs/outputs fp32.
static constexpr float SCALE = 0.17677669529663687f;          // 1/sqrt(32)
static constexpr float C2    = 0.17677669529663687f / 4096.f; // (scale/L) = c^2

__device__ __forceinline__ float bf2f(u16 u){
  union { u32 i; float f; } v; v.i = ((u32)u) << 16; return v.f;
}
__device__ __forceinline__ u16 f2bf(float f){
  union { float fl; u32 i; } v; v.fl = f;
  u32 r = v.i + 0x7fffu + ((v.i >> 16) & 1u);   // RNE
  return (u16)(r >> 16);
}
__device__ __forceinline__ float eluP(float x){ return x > 0.f ? x + 1.f : expf(x); }
__device__ __forceinline__ float rfreq(int j){
  const float t[8] = {1.f, 0.2682695795f, 0.0719685673f, 0.0193069773f,
                      0.0051794747f, 0.0013894955f, 0.0003727594f, 1e-4f};
  return t[j];
}

// ---------------- weight split: fp32 -> bf16 hi/lo, keep [m][k] ----------------
__global__ __launch_bounds__(256) void k_prep(
    const float* __restrict__ qw, const float* __restrict__ pw,
    u16* __restrict__ Whi, u16* __restrict__ Wlo,
    u16* __restrict__ Phi, u16* __restrict__ Plo)
{
  int idx = blockIdx.x * 256 + threadIdx.x;
  if (idx < 262144){
    float v = qw[idx]; u16 h = f2bf(v);
    Whi[idx] = h; Wlo[idx] = f2bf(v - bf2f(h));
  }
  if (idx < 65536){
    float v = pw[idx]; u16 h = f2bf(v);
    Phi[idx] = h; Plo[idx] = f2bf(v - bf2f(h));
  }
}

// ---------------- x [b][c][l] fp32 -> XThi/XTlo [b][l][c] bf16 ----------------
__global__ __launch_bounds__(256) void k_xt(
    const float* __restrict__ x, u16* __restrict__ XThi, u16* __restrict__ XTlo)
{
  __shared__ float t[64][65];
  int l0 = blockIdx.x * 64, c0 = blockIdx.y * 64, b = blockIdx.z;
  const float* xp = x + (((long)b * 256 + c0) << 12) + l0;
  #pragma unroll
  for (int rep = 0; rep < 4; rep++){
    int idx = threadIdx.x + rep * 256;
    int r = idx >> 4, ch = (idx & 15) * 4;
    float4 f = *(const float4*)&xp[((long)r << 12) + ch];
    t[r][ch] = f.x; t[r][ch+1] = f.y; t[r][ch+2] = f.z; t[r][ch+3] = f.w;
  }
  __syncthreads();
  int r2 = threadIdx.x >> 2, c8 = (threadIdx.x & 3) * 16;
  u32 whi[8], wlo[8];
  #pragma unroll
  for (int j = 0; j < 8; j++){
    float v0 = t[c8 + 2*j][r2], v1 = t[c8 + 2*j + 1][r2];
    u16 h0 = f2bf(v0), h1 = f2bf(v1);
    u16 l0b = f2bf(v0 - bf2f(h0)), l1b = f2bf(v1 - bf2f(h1));
    whi[j] = (u32)h0 | ((u32)h1 << 16);
    wlo[j] = (u32)l0b | ((u32)l1b << 16);
  }
  long ob = (((long)b << 12) << 8) + ((long)(l0 + r2) << 8) + c0 + c8;
  *(uint4*)&XThi[ob]     = make_uint4(whi[0], whi[1], whi[2], whi[3]);
  *(uint4*)&XThi[ob + 8] = make_uint4(whi[4], whi[5], whi[6], whi[7]);
  *(uint4*)&XTlo[ob]     = make_uint4(wlo[0], wlo[1], wlo[2], wlo[3]);
  *(uint4*)&XTlo[ob + 8] = make_uint4(wlo[4], wlo[5], wlo[6], wlo[7]);
}

// ---------------- qkvo GEMM (triple-product) + fused means + fused rope-on-K ----------------
// outputs single-bf16 [b][c][l]; KMb/VMb get raw column sums (pre-rope, post-elu)
__global__ __launch_bounds__(256) void k_gemmA(
    const u16* __restrict__ Whi_, const u16* __restrict__ Wlo_,
    const u16* __restrict__ Bhi_, const u16* __restrict__ Blo_,
    const float* __restrict__ bias,
    u16* __restrict__ Q16, u16* __restrict__ K16,
    u16* __restrict__ V16, u16* __restrict__ O16,
    float* __restrict__ KMb, float* __restrict__ VMb)
{
  __shared__ __align__(16) u16 Ah[128 * 40];
  __shared__ __align__(16) u16 Al[128 * 40];
  __shared__ __align__(16) u16 Bh[128 * 40];
  __shared__ __align__(16) u16 Bl[128 * 40];
  __shared__ float scs[2][8][64];
  const int tid = threadIdx.x;
  const int nt = blockIdx.x, mt = blockIdx.y, b = blockIdx.z;
  const int m0 = mt * 128, n0 = nt * 128;
  const int wave = tid >> 6, lane = tid & 63;
  const int wm = wave & 1, wn = wave >> 1, qu = lane >> 4, ln = lane & 15;

  // sincos table (ready after first __syncthreads)
  #pragma unroll
  for (int r = 0; r < 2; r++){
    int idx = tid + r * 256;
    int jj = idx >> 6, pp = idx & 63;
    float sn, cs; sincosf(rfreq(jj) * (float)pp, &sn, &cs);
    scs[0][jj][pp] = sn; scs[1][jj][pp] = cs;
  }

  const long bOff = ((long)b << 12) << 8;
  const u16* bhp = Bhi_ + bOff;
  const u16* blp = Blo_ + bOff;

  f32x4 acc[4][4];
  #pragma unroll
  for (int im = 0; im < 4; im++)
    #pragma unroll
    for (int in = 0; in < 4; in++)
      #pragma unroll
      for (int r = 0; r < 4; r++) acc[im][in][r] = 0.f;

  for (int kk = 0; kk < 256; kk += 32){
    #pragma unroll
    for (int rep = 0; rep < 2; rep++){
      int r = (tid >> 2) + rep * 64;
      int c = (tid & 3) * 8;
      int ga = (m0 + r) * 256 + kk + c;
      long gb = (long)(n0 + r) * 256 + kk + c;
      *(short8*)&Ah[r * 40 + c] = *(const short8*)&Whi_[ga];
      *(short8*)&Al[r * 40 + c] = *(const short8*)&Wlo_[ga];
      *(short8*)&Bh[r * 40 + c] = *(const short8*)&bhp[gb];
      *(short8*)&Bl[r * 40 + c] = *(const short8*)&blp[gb];
    }
    __syncthreads();
    short8 fbh[4], fbl[4];
    #pragma unroll
    for (int in = 0; in < 4; in++){
      int row = wn * 64 + in * 16 + ln;
      fbh[in] = *(short8*)&Bh[row * 40 + qu * 8];
      fbl[in] = *(short8*)&Bl[row * 40 + qu * 8];
    }
    #pragma unroll
    for (int im = 0; im < 4; im++){
      int row = wm * 64 + im * 16 + ln;
      short8 fah = *(short8*)&Ah[row * 40 + qu * 8];
      short8 fal = *(short8*)&Al[row * 40 + qu * 8];
      #pragma unroll
      for (int in = 0; in < 4; in++){
        acc[im][in] = __builtin_amdgcn_mfma_f32_16x16x32_bf16(fah, fbh[in], acc[im][in], 0, 0, 0);
        acc[im][in] = __builtin_amdgcn_mfma_f32_16x16x32_bf16(fah, fbl[in], acc[im][in], 0, 0, 0);
        acc[im][in] = __builtin_amdgcn_mfma_f32_16x16x32_bf16(fal, fbh[in], acc[im][in], 0, 0, 0);
      }
    }
    __syncthreads();
  }

  // epilogue: C/D layout col = lane&15 (n), row = quad*4 + reg (m)
  const int range = m0 >> 8;                 // 0:q 1:k 2:v 3:o (block-uniform)
  u16* dst = (range == 0) ? Q16 : (range == 1) ? K16 : (range == 2) ? V16 : O16;
  #pragma unroll
  for (int im = 0; im < 4; im++){
    const int mb = m0 + wm * 64 + im * 16 + qu * 4;
    float v[4][4];
    #pragma unroll
    for (int r = 0; r < 4; r++){
      float bia = bias[mb + r];
      #pragma unroll
      for (int in = 0; in < 4; in++){
        float t = acc[im][in][r] + bia;
        v[r][in] = (range < 2) ? eluP(t) : t;
      }
    }
    if (range == 1 || range == 2){
      float* mbuf = (range == 1) ? KMb : VMb;
      #pragma unroll
      for (int r = 0; r < 4; r++){
        float s = v[r][0] + v[r][1] + v[r][2] + v[r][3];
        s += __shfl_xor(s, 1); s += __shfl_xor(s, 2);
        s += __shfl_xor(s, 4); s += __shfl_xor(s, 8);
        if (ln == 0) atomicAdd(&mbuf[b * 256 + ((mb + r) & 255)], s);
      }
    }
    if (range == 1){
      const int p0 = (mb & 31) >> 1;         // pairs (r0,r1)->p0, (r2,r3)->p0+1
      #pragma unroll
      for (int half = 0; half < 2; half++){
        int p = p0 + half, j = p & 7;
        #pragma unroll
        for (int in = 0; in < 4; in++){
          int n = n0 + wn * 64 + in * 16 + ln;
          int pos = (p < 8) ? (n >> 6) : (n & 63);
          float sn = scs[0][j][pos], cs = scs[1][j][pos];
          float a = v[2*half][in], bb = v[2*half+1][in];
          v[2*half][in]   = a * cs - bb * sn;
          v[2*half+1][in] = bb * cs + a * sn;
        }
      }
    }
    #pragma unroll
    for (int r = 0; r < 4; r++){
      u16* rowp = dst + (((long)b * 256 + ((mb + r) & 255)) << 12);
      #pragma unroll
      for (int in = 0; in < 4; in++){
        int n = n0 + wn * 64 + in * 16 + ln;
        rowp[n] = f2bf(v[r][in]);
      }
    }
  }
}

// ---------------- kv via MFMA: kv[b,n,d,e] = c2 * sum_l Kr[d][l] V[e][l] ----------------
// grid (8 n, 8 b), 4 waves split l into 1024 each; mfma_32x32x16_bf16
__global__ __launch_bounds__(256) void k_kv(
    const u16* __restrict__ K16, const u16* __restrict__ V16, float* __restrict__ KVb)
{
  __shared__ float red[4][1024];
  const int n = blockIdx.x, b = blockIdx.y;
  const int tid = threadIdx.x, wave = tid >> 6, lane = tid & 63;
  const u16* kp = K16 + (((long)(b * 256 + n * 32)) << 12);
  const u16* vp = V16 + (((long)(b * 256 + n * 32)) << 12);
  const int m = lane & 31, kh = lane >> 5;
  const long row = ((long)m << 12);

  f32x16 acc;
  #pragma unroll
  for (int r = 0; r < 16; r++) acc[r] = 0.f;
  #pragma unroll 4
  for (int it = 0; it < 64; it++){
    int l = wave * 1024 + it * 16 + kh * 8;
    short8 a  = *(const short8*)&kp[row + l];
    short8 bf = *(const short8*)&vp[row + l];
    acc = __builtin_amdgcn_mfma_f32_32x32x16_bf16(a, bf, acc, 0, 0, 0);
  }
  // C/D 32x32: col = lane&31, row = (reg&3) + 8*(reg>>2) + 4*(lane>>5)
  #pragma unroll
  for (int reg = 0; reg < 16; reg++){
    int rr = (reg & 3) + 8 * (reg >> 2) + 4 * kh;
    red[wave][rr * 32 + m] = acc[reg];
  }
  __syncthreads();
  #pragma unroll
  for (int i = tid; i < 1024; i += 256){
    float s = red[0][i] + red[1][i] + red[2][i] + red[3][i];
    KVb[(((long)b * 8 + n) << 10) + i] = s * C2;
  }
}

// ---------------- lepe = depthwise 5x5 (pad 2) of V (bf16) -> Tb16 ----------------
__global__ __launch_bounds__(256) void k_lepe(
    const u16* __restrict__ V16, const float* __restrict__ lw,
    const float* __restrict__ lb, u16* __restrict__ Tb16)
{
  __shared__ float tile[20][68];
  __shared__ float wl[25];
  int ht = blockIdx.x, ch = blockIdx.y, b = blockIdx.z;
  int h0 = ht * 16;
  const u16* vp = V16 + (((long)b * 256 + ch) << 12);
  if (threadIdx.x < 25) wl[threadIdx.x] = lw[ch * 25 + threadIdx.x];
  for (int idx = threadIdx.x; idx < 20 * 68; idx += 256){
    int r = idx / 68, c = idx % 68;
    int gh = h0 + r - 2, gw = c - 2;
    float v = 0.f;
    if (gh >= 0 && gh < 64 && gw >= 0 && gw < 64) v = bf2f(vp[(gh << 6) + gw]);
    tile[r][c] = v;
  }
  __syncthreads();
  const float bia = lb[ch];
  #pragma unroll
  for (int r2 = 0; r2 < 4; r2++){
    int idx = threadIdx.x + r2 * 256;
    int oh = idx >> 6, ow = idx & 63;
    float s = bia;
    #pragma unroll
    for (int i = 0; i < 5; i++)
      #pragma unroll
      for (int j = 0; j < 5; j++) s += tile[oh + i][ow + j] * wl[i * 5 + j];
    Tb16[(((long)b * 256 + ch) << 12) + ((h0 + oh) << 6) + ow] = f2bf(s);
  }
}

// ---------------- res (+fused z): TT16[b][l][c] = ((q.kv)*f - z*vm + lepe) * o ----------------
// grid (16 lt, 8 n, 8 b), 1 l per thread
__global__ __launch_bounds__(256) void k_res(
    const u16* __restrict__ Q16, const float* __restrict__ KMb,
    const float* __restrict__ KVb, const float* __restrict__ VMb,
    const u16* __restrict__ O16, const u16* __restrict__ Tb16,
    u16* __restrict__ TT16)
{
  __shared__ __align__(16) float kvs[1024];
  __shared__ float scs[2][8][64];
  __shared__ float kms[32], vms[32];
  const int b = blockIdx.z, n = blockIdx.y, tid = threadIdx.x;
  #pragma unroll
  for (int r = 0; r < 2; r++){
    int idx = tid + r * 256;
    int jj = idx >> 6, pp = idx & 63;
    float sn, cs; sincosf(rfreq(jj) * (float)pp, &sn, &cs);
    scs[0][jj][pp] = sn; scs[1][jj][pp] = cs;
  }
  {
    const float* kv = KVb + (((long)b * 8 + n) << 10);
    #pragma unroll
    for (int r = 0; r < 4; r++) kvs[tid + r * 256] = kv[tid + r * 256];
    if (tid < 32){
      kms[tid] = KMb[b * 256 + n * 32 + tid] * (1.f / 4096.f);
      vms[tid] = VMb[b * 256 + n * 32 + tid] * (1.f / 4096.f);
    }
  }
  __syncthreads();

  const int l = blockIdx.x * 256 + tid;
  const long cbase = ((long)(b * 256 + n * 32)) << 12;

  float q[32];
  #pragma unroll
  for (int d = 0; d < 32; d++) q[d] = bf2f(Q16[cbase + ((long)d << 12) + l]);
  float z = 0.f;
  #pragma unroll
  for (int d = 0; d < 32; d++) z += q[d] * kms[d];
  z *= SCALE;
  #pragma unroll
  for (int p = 0; p < 16; p++){
    int pos = (p < 8) ? (l >> 6) : (l & 63);
    float sn = scs[0][p & 7][pos], cs = scs[1][p & 7][pos];
    float q0 = q[2*p], q1 = q[2*p+1];
    q[2*p]   = q0 * cs - q1 * sn;
    q[2*p+1] = q1 * cs + q0 * sn;
  }

  float acc[32];
  #pragma unroll
  for (int e = 0; e < 32; e++) acc[e] = 0.f;
  #pragma unroll 8
  for (int d = 0; d < 32; d++){
    float qd = q[d];
    #pragma unroll
    for (int ec = 0; ec < 8; ec++){
      float4 kvv = *(float4*)&kvs[d * 32 + ec * 4];
      acc[ec*4+0] += qd * kvv.x;
      acc[ec*4+1] += qd * kvv.y;
      acc[ec*4+2] += qd * kvv.z;
      acc[ec*4+3] += qd * kvv.w;
    }
  }

  const float f = 1.f + 1.f / (z + 1e-6f);
  u32 w[16];
  #pragma unroll
  for (int e = 0; e < 32; e++){
    long off = cbase + ((long)e << 12) + l;
    float val = (acc[e] * f - z * vms[e] + bf2f(Tb16[off])) * bf2f(O16[off]);
    u16 h = f2bf(val);
    if (e & 1) w[e >> 1] |= ((u32)h << 16);
    else       w[e >> 1] = h;
  }
  long ob = (((long)b << 12) << 8) + ((long)l << 8) + n * 32;
  #pragma unroll
  for (int j = 0; j < 4; j++)
    *(uint4*)&TT16[ob + j * 8] = make_uint4(w[4*j], w[4*j+1], w[4*j+2], w[4*j+3]);
}

// ---------------- proj GEMM: A hi/lo x B single-bf16 -> fp32 out ----------------
__global__ __launch_bounds__(256) void k_gemmP(
    const u16* __restrict__ Phi_, const u16* __restrict__ Plo_,
    const u16* __restrict__ TT16, const float* __restrict__ bias,
    float* __restrict__ out)
{
  __shared__ __align__(16) u16 Ah[128 * 40];
  __shared__ __align__(16) u16 Al[128 * 40];
  __shared__ __align__(16) u16 Bh[128 * 40];
  const int tid = threadIdx.x;
  const int nt = blockIdx.x, mt = blockIdx.y, b = blockIdx.z;
  const int m0 = mt * 128, n0 = nt * 128;
  const int wave = tid >> 6, lane = tid & 63;
  const int wm = wave & 1, wn = wave >> 1, qu = lane >> 4, ln = lane & 15;

  const u16* bhp = TT16 + (((long)b << 12) << 8);

  f32x4 acc[4][4];
  #pragma unroll
  for (int im = 0; im < 4; im++)
    #pragma unroll
    for (int in = 0; in < 4; in++)
      #pragma unroll
      for (int r = 0; r < 4; r++) acc[im][in][r] = 0.f;

  for (int kk = 0; kk < 256; kk += 32){
    #pragma unroll
    for (int rep = 0; rep < 2; rep++){
      int r = (tid >> 2) + rep * 64;
      int c = (tid & 3) * 8;
      int ga = (m0 + r) * 256 + kk + c;
      long gb = (long)(n0 + r) * 256 + kk + c;
      *(short8*)&Ah[r * 40 + c] = *(const short8*)&Phi_[ga];
      *(short8*)&Al[r * 40 + c] = *(const short8*)&Plo_[ga];
      *(short8*)&Bh[r * 40 + c] = *(const short8*)&bhp[gb];
    }
    __syncthreads();
    short8 fbh[4];
    #pragma unroll
    for (int in = 0; in < 4; in++){
      int row = wn * 64 + in * 16 + ln;
      fbh[in] = *(short8*)&Bh[row * 40 + qu * 8];
    }
    #pragma unroll
    for (int im = 0; im < 4; im++){
      int row = wm * 64 + im * 16 + ln;
      short8 fah = *(short8*)&Ah[row * 40 + qu * 8];
      short8 fal = *(short8*)&Al[row * 40 + qu * 8];
      #pragma unroll
      for (int in = 0; in < 4; in++){
        acc[im][in] = __builtin_amdgcn_mfma_f32_16x16x32_bf16(fah, fbh[in], acc[im][in], 0, 0, 0);
        acc[im][in] = __builtin_amdgcn_mfma_f32_16x16x32_bf16(fal, fbh[in], acc[im][in], 0, 0, 0);
      }
    }
    __syncthreads();
  }
  #pragma unroll
  for (int im = 0; im < 4; im++){
    int mbase = m0 + wm * 64 + im * 16 + qu * 4;
    #pragma unroll
    for (int r = 0; r < 4; r++){
      int m = mbase + r;
      float bia = bias[m];
      float* row = out + (((long)b * 256 + m) << 12);
      #pragma unroll
      for (int in = 0; in < 4; in++){
        int n = n0 + wn * 64 + in * 16 + ln;
        row[n] = acc[im][in][r] + bia;
      }
    }
  }
}

extern "C" void kernel_launch(void* const* d_in, const int* in_sizes, int n_in,
                              void* d_out, int out_size, void* d_ws, size_t ws_size,
                              hipStream_t stream)
{
  const float* x  = (const float*)d_in[0];
  const float* qw = (const float*)d_in[1];
  const float* qb = (const float*)d_in[2];
  const float* lw = (const float*)d_in[3];
  const float* lb = (const float*)d_in[4];
  const float* pw = (const float*)d_in[5];
  const float* pb = (const float*)d_in[6];

  u16* W    = (u16*)d_ws;
  u16* Q16  = W;                          // 8*256*4096 u16 = 8,388,608 each
  u16* K16  = Q16 + 8388608;
  u16* V16  = K16 + 8388608;
  u16* O16  = V16 + 8388608;
  u16* Tb16 = O16 + 8388608;
  u16* XThi = Tb16 + 8388608;             // reused as TT16 after k_gemmA
  u16* XTlo = XThi + 8388608;
  u16* Whi  = XTlo + 8388608;             // 262144
  u16* Wlo  = Whi + 262144;
  u16* Phi  = Wlo + 262144;               // 65536
  u16* Plo  = Phi + 65536;
  float* KMb = (float*)(Plo + 65536);     // 2048
  float* VMb = KMb + 2048;                // 2048
  float* KVb = VMb + 2048;                // 65536
  size_t total_bytes = (7ull*8388608 + 2*262144 + 2*65536) * 2 + (2048+2048+65536) * 4;
  if (ws_size < total_bytes) return;

  u16* TT16 = XThi;

  hipMemsetAsync(KMb, 0, 4096 * 4, stream);   // KMb + VMb raw sums
  k_prep<<<1024, 256, 0, stream>>>(qw, pw, Whi, Wlo, Phi, Plo);
  k_xt<<<dim3(64, 4, 8), 256, 0, stream>>>(x, XThi, XTlo);
  k_gemmA<<<dim3(32, 8, 8), 256, 0, stream>>>(Whi, Wlo, XThi, XTlo, qb,
                                              Q16, K16, V16, O16, KMb, VMb);
  k_kv<<<dim3(8, 8), 256, 0, stream>>>(K16, V16, KVb);
  k_lepe<<<dim3(4, 256, 8), 256, 0, stream>>>(V16, lw, lb, Tb16);
  k_res<<<dim3(16, 8, 8), 256, 0, stream>>>(Q16, KMb, KVb, VMb, O16, Tb16, TT16);
  k_gemmP<<<dim3(32, 2, 8), 256, 0, stream>>>(Phi, Plo, TT16, pb, (float*)d_out);
}

// Round 6
// 272.149 us; speedup vs baseline: 1.8076x; 1.0170x over previous
//
#include <hip/hip_runtime.h>
#include <math.h>

typedef unsigned short u16;
typedef unsigned int u32;
typedef __attribute__((ext_vector_type(8))) short short8;
typedef __attribute__((ext_vector_type(4))) float f32x4;
typedef __attribute__((ext_vector_type(16))) float f32x16;

// B=8, C=256, H=W=64, L=4096, NH=8, HD=32. Inputs/outputs fp32.
static constexpr float SCALE = 0.17677669529663687f;          // 1/sqrt(32)
static constexpr float C2    = 0.17677669529663687f / 4096.f; // (scale/L) = c^2

__device__ __forceinline__ float bf2f(u16 u){
  union { u32 i; float f; } v; v.i = ((u32)u) << 16; return v.f;
}
__device__ __forceinline__ u16 f2bf(float f){
  union { float fl; u32 i; } v; v.fl = f;
  u32 r = v.i + 0x7fffu + ((v.i >> 16) & 1u);   // RNE
  return (u16)(r >> 16);
}
__device__ __forceinline__ float eluP(float x){ return x > 0.f ? x + 1.f : expf(x); }
__device__ __forceinline__ float rfreq(int j){
  const float t[8] = {1.f, 0.2682695795f, 0.0719685673f, 0.0193069773f,
                      0.0051794747f, 0.0013894955f, 0.0003727594f, 1e-4f};
  return t[j];
}
// async global->LDS, 16B per lane; lds base must be wave-uniform
__device__ __forceinline__ void gload16(const u16* g, u16* l){
  __builtin_amdgcn_global_load_lds(
      (const __attribute__((address_space(1))) u32*)g,
      (__attribute__((address_space(3))) u32*)l, 16, 0, 0);
}

// ---------------- weight split: fp32 -> bf16 hi/lo, keep [m][k] ----------------
__global__ __launch_bounds__(256) void k_prep(
    const float* __restrict__ qw, const float* __restrict__ pw,
    u16* __restrict__ Whi, u16* __restrict__ Wlo,
    u16* __restrict__ Phi, u16* __restrict__ Plo)
{
  int idx = blockIdx.x * 256 + threadIdx.x;
  if (idx < 262144){
    float v = qw[idx]; u16 h = f2bf(v);
    Whi[idx] = h; Wlo[idx] = f2bf(v - bf2f(h));
  }
  if (idx < 65536){
    float v = pw[idx]; u16 h = f2bf(v);
    Phi[idx] = h; Plo[idx] = f2bf(v - bf2f(h));
  }
}

// ---------------- x [b][c][l] fp32 -> XThi/XTlo [b][l][c] bf16 ----------------
__global__ __launch_bounds__(256) void k_xt(
    const float* __restrict__ x, u16* __restrict__ XThi, u16* __restrict__ XTlo)
{
  __shared__ float t[64][65];
  int l0 = blockIdx.x * 64, c0 = blockIdx.y * 64, b = blockIdx.z;
  const float* xp = x + (((long)b * 256 + c0) << 12) + l0;
  #pragma unroll
  for (int rep = 0; rep < 4; rep++){
    int idx = threadIdx.x + rep * 256;
    int r = idx >> 4, ch = (idx & 15) * 4;
    float4 f = *(const float4*)&xp[((long)r << 12) + ch];
    t[r][ch] = f.x; t[r][ch+1] = f.y; t[r][ch+2] = f.z; t[r][ch+3] = f.w;
  }
  __syncthreads();
  int r2 = threadIdx.x >> 2, c8 = (threadIdx.x & 3) * 16;
  u32 whi[8], wlo[8];
  #pragma unroll
  for (int j = 0; j < 8; j++){
    float v0 = t[c8 + 2*j][r2], v1 = t[c8 + 2*j + 1][r2];
    u16 h0 = f2bf(v0), h1 = f2bf(v1);
    u16 l0b = f2bf(v0 - bf2f(h0)), l1b = f2bf(v1 - bf2f(h1));
    whi[j] = (u32)h0 | ((u32)h1 << 16);
    wlo[j] = (u32)l0b | ((u32)l1b << 16);
  }
  long ob = (((long)b << 12) << 8) + ((long)(l0 + r2) << 8) + c0 + c8;
  *(uint4*)&XThi[ob]     = make_uint4(whi[0], whi[1], whi[2], whi[3]);
  *(uint4*)&XThi[ob + 8] = make_uint4(whi[4], whi[5], whi[6], whi[7]);
  *(uint4*)&XTlo[ob]     = make_uint4(wlo[0], wlo[1], wlo[2], wlo[3]);
  *(uint4*)&XTlo[ob + 8] = make_uint4(wlo[4], wlo[5], wlo[6], wlo[7]);
}

// ---------------- qkvo GEMM (triple-product), global_load_lds staging ----------------
// LDS tiles packed [128][32] u16, XOR chunk swizzle: LDS chunk c of row r = global chunk c^(r&3)
__global__ __launch_bounds__(256) void k_gemmA(
    const u16* __restrict__ Whi_, const u16* __restrict__ Wlo_,
    const u16* __restrict__ Bhi_, const u16* __restrict__ Blo_,
    const float* __restrict__ bias,
    u16* __restrict__ Q16, u16* __restrict__ K16,
    u16* __restrict__ V16, u16* __restrict__ O16,
    float* __restrict__ KMb, float* __restrict__ VMb)
{
  __shared__ __align__(16) u16 AhS[4096];
  __shared__ __align__(16) u16 AlS[4096];
  __shared__ __align__(16) u16 BhS[4096];
  __shared__ __align__(16) u16 BlS[4096];
  __shared__ float scs[2][8][64];
  const int tid = threadIdx.x;
  const int nt = blockIdx.x, mt = blockIdx.y, b = blockIdx.z;
  const int m0 = mt * 128, n0 = nt * 128;
  const int wave = tid >> 6, lane = tid & 63;
  const int wm = wave & 1, wn = wave >> 1, qu = lane >> 4, ln = lane & 15;

  #pragma unroll
  for (int r = 0; r < 2; r++){
    int idx = tid + r * 256;
    int jj = idx >> 6, pp = idx & 63;
    float sn, cs; sincosf(rfreq(jj) * (float)pp, &sn, &cs);
    scs[0][jj][pp] = sn; scs[1][jj][pp] = cs;
  }

  const long bOff = ((long)b << 12) << 8;
  const u16* bhp = Bhi_ + bOff;
  const u16* blp = Blo_ + bOff;

  // staging lane geometry
  const int l4 = lane >> 2, c4 = lane & 3;
  const int gch = (c4 ^ (l4 & 3)) * 8;            // swizzled global col chunk (elements)
  // fragment read swizzle: chunk = qu ^ (row&3), row&3 == ln&3
  const int fch = (qu ^ (ln & 3)) * 8;

  f32x4 acc[4][4];
  #pragma unroll
  for (int im = 0; im < 4; im++)
    #pragma unroll
    for (int in = 0; in < 4; in++)
      #pragma unroll
      for (int r = 0; r < 4; r++) acc[im][in][r] = 0.f;

  for (int kk = 0; kk < 256; kk += 32){
    #pragma unroll
    for (int t = 0; t < 2; t++){
      int rw = wave * 32 + t * 16;                // window base row
      int ga = (m0 + rw + l4) * 256 + kk + gch;
      long gb = (long)(n0 + rw + l4) * 256 + kk + gch;
      u16* la = &AhS[rw * 32];
      gload16(&Whi_[ga], la);
      gload16(&Wlo_[ga], &AlS[rw * 32]);
      gload16(&bhp[gb],  &BhS[rw * 32]);
      gload16(&blp[gb],  &BlS[rw * 32]);
    }
    __syncthreads();
    short8 fbh[4], fbl[4];
    #pragma unroll
    for (int in = 0; in < 4; in++){
      int row = wn * 64 + in * 16 + ln;
      fbh[in] = *(short8*)&BhS[row * 32 + fch];
      fbl[in] = *(short8*)&BlS[row * 32 + fch];
    }
    #pragma unroll
    for (int im = 0; im < 4; im++){
      int row = wm * 64 + im * 16 + ln;
      short8 fah = *(short8*)&AhS[row * 32 + fch];
      short8 fal = *(short8*)&AlS[row * 32 + fch];
      #pragma unroll
      for (int in = 0; in < 4; in++){
        acc[im][in] = __builtin_amdgcn_mfma_f32_16x16x32_bf16(fah, fbh[in], acc[im][in], 0, 0, 0);
        acc[im][in] = __builtin_amdgcn_mfma_f32_16x16x32_bf16(fah, fbl[in], acc[im][in], 0, 0, 0);
        acc[im][in] = __builtin_amdgcn_mfma_f32_16x16x32_bf16(fal, fbh[in], acc[im][in], 0, 0, 0);
      }
    }
    __syncthreads();
  }

  // epilogue: C/D layout col = lane&15 (n), row = quad*4 + reg (m)
  const int range = m0 >> 8;                 // 0:q 1:k 2:v 3:o (block-uniform)
  u16* dst = (range == 0) ? Q16 : (range == 1) ? K16 : (range == 2) ? V16 : O16;
  #pragma unroll
  for (int im = 0; im < 4; im++){
    const int mb = m0 + wm * 64 + im * 16 + qu * 4;
    float v[4][4];
    #pragma unroll
    for (int r = 0; r < 4; r++){
      float bia = bias[mb + r];
      #pragma unroll
      for (int in = 0; in < 4; in++){
        float t = acc[im][in][r] + bia;
        v[r][in] = (range < 2) ? eluP(t) : t;
      }
    }
    if (range == 1 || range == 2){
      float* mbuf = (range == 1) ? KMb : VMb;
      #pragma unroll
      for (int r = 0; r < 4; r++){
        float s = v[r][0] + v[r][1] + v[r][2] + v[r][3];
        s += __shfl_xor(s, 1); s += __shfl_xor(s, 2);
        s += __shfl_xor(s, 4); s += __shfl_xor(s, 8);
        if (ln == 0) atomicAdd(&mbuf[b * 256 + ((mb + r) & 255)], s);
      }
    }
    if (range == 1){
      const int p0 = (mb & 31) >> 1;
      #pragma unroll
      for (int half = 0; half < 2; half++){
        int p = p0 + half, j = p & 7;
        #pragma unroll
        for (int in = 0; in < 4; in++){
          int n = n0 + wn * 64 + in * 16 + ln;
          int pos = (p < 8) ? (n >> 6) : (n & 63);
          float sn = scs[0][j][pos], cs = scs[1][j][pos];
          float a = v[2*half][in], bb = v[2*half+1][in];
          v[2*half][in]   = a * cs - bb * sn;
          v[2*half+1][in] = bb * cs + a * sn;
        }
      }
    }
    #pragma unroll
    for (int r = 0; r < 4; r++){
      u16* rowp = dst + (((long)b * 256 + ((mb + r) & 255)) << 12);
      #pragma unroll
      for (int in = 0; in < 4; in++){
        int n = n0 + wn * 64 + in * 16 + ln;
        rowp[n] = f2bf(v[r][in]);
      }
    }
  }
}

// ---------------- kv via MFMA (unchanged) ----------------
__global__ __launch_bounds__(256) void k_kv(
    const u16* __restrict__ K16, const u16* __restrict__ V16, float* __restrict__ KVb)
{
  __shared__ float red[4][1024];
  const int n = blockIdx.x, b = blockIdx.y;
  const int tid = threadIdx.x, wave = tid >> 6, lane = tid & 63;
  const u16* kp = K16 + (((long)(b * 256 + n * 32)) << 12);
  const u16* vp = V16 + (((long)(b * 256 + n * 32)) << 12);
  const int m = lane & 31, kh = lane >> 5;
  const long row = ((long)m << 12);

  f32x16 acc;
  #pragma unroll
  for (int r = 0; r < 16; r++) acc[r] = 0.f;
  #pragma unroll 4
  for (int it = 0; it < 64; it++){
    int l = wave * 1024 + it * 16 + kh * 8;
    short8 a  = *(const short8*)&kp[row + l];
    short8 bf = *(const short8*)&vp[row + l];
    acc = __builtin_amdgcn_mfma_f32_32x32x16_bf16(a, bf, acc, 0, 0, 0);
  }
  #pragma unroll
  for (int reg = 0; reg < 16; reg++){
    int rr = (reg & 3) + 8 * (reg >> 2) + 4 * kh;
    red[wave][rr * 32 + m] = acc[reg];
  }
  __syncthreads();
  #pragma unroll
  for (int i = tid; i < 1024; i += 256){
    float s = red[0][i] + red[1][i] + red[2][i] + red[3][i];
    KVb[(((long)b * 8 + n) << 10) + i] = s * C2;
  }
}

// ---------------- lepe (unchanged) ----------------
__global__ __launch_bounds__(256) void k_lepe(
    const u16* __restrict__ V16, const float* __restrict__ lw,
    const float* __restrict__ lb, u16* __restrict__ Tb16)
{
  __shared__ float tile[20][68];
  __shared__ float wl[25];
  int ht = blockIdx.x, ch = blockIdx.y, b = blockIdx.z;
  int h0 = ht * 16;
  const u16* vp = V16 + (((long)b * 256 + ch) << 12);
  if (threadIdx.x < 25) wl[threadIdx.x] = lw[ch * 25 + threadIdx.x];
  for (int idx = threadIdx.x; idx < 20 * 68; idx += 256){
    int r = idx / 68, c = idx % 68;
    int gh = h0 + r - 2, gw = c - 2;
    float v = 0.f;
    if (gh >= 0 && gh < 64 && gw >= 0 && gw < 64) v = bf2f(vp[(gh << 6) + gw]);
    tile[r][c] = v;
  }
  __syncthreads();
  const float bia = lb[ch];
  #pragma unroll
  for (int r2 = 0; r2 < 4; r2++){
    int idx = threadIdx.x + r2 * 256;
    int oh = idx >> 6, ow = idx & 63;
    float s = bia;
    #pragma unroll
    for (int i = 0; i < 5; i++)
      #pragma unroll
      for (int j = 0; j < 5; j++) s += tile[oh + i][ow + j] * wl[i * 5 + j];
    Tb16[(((long)b * 256 + ch) << 12) + ((h0 + oh) << 6) + ow] = f2bf(s);
  }
}

// ---------------- res (+fused z) (unchanged) ----------------
__global__ __launch_bounds__(256) void k_res(
    const u16* __restrict__ Q16, const float* __restrict__ KMb,
    const float* __restrict__ KVb, const float* __restrict__ VMb,
    const u16* __restrict__ O16, const u16* __restrict__ Tb16,
    u16* __restrict__ TT16)
{
  __shared__ __align__(16) float kvs[1024];
  __shared__ float scs[2][8][64];
  __shared__ float kms[32], vms[32];
  const int b = blockIdx.z, n = blockIdx.y, tid = threadIdx.x;
  #pragma unroll
  for (int r = 0; r < 2; r++){
    int idx = tid + r * 256;
    int jj = idx >> 6, pp = idx & 63;
    float sn, cs; sincosf(rfreq(jj) * (float)pp, &sn, &cs);
    scs[0][jj][pp] = sn; scs[1][jj][pp] = cs;
  }
  {
    const float* kv = KVb + (((long)b * 8 + n) << 10);
    #pragma unroll
    for (int r = 0; r < 4; r++) kvs[tid + r * 256] = kv[tid + r * 256];
    if (tid < 32){
      kms[tid] = KMb[b * 256 + n * 32 + tid] * (1.f / 4096.f);
      vms[tid] = VMb[b * 256 + n * 32 + tid] * (1.f / 4096.f);
    }
  }
  __syncthreads();

  const int l = blockIdx.x * 256 + tid;
  const long cbase = ((long)(b * 256 + n * 32)) << 12;

  float q[32];
  #pragma unroll
  for (int d = 0; d < 32; d++) q[d] = bf2f(Q16[cbase + ((long)d << 12) + l]);
  float z = 0.f;
  #pragma unroll
  for (int d = 0; d < 32; d++) z += q[d] * kms[d];
  z *= SCALE;
  #pragma unroll
  for (int p = 0; p < 16; p++){
    int pos = (p < 8) ? (l >> 6) : (l & 63);
    float sn = scs[0][p & 7][pos], cs = scs[1][p & 7][pos];
    float q0 = q[2*p], q1 = q[2*p+1];
    q[2*p]   = q0 * cs - q1 * sn;
    q[2*p+1] = q1 * cs + q0 * sn;
  }

  float acc[32];
  #pragma unroll
  for (int e = 0; e < 32; e++) acc[e] = 0.f;
  #pragma unroll 8
  for (int d = 0; d < 32; d++){
    float qd = q[d];
    #pragma unroll
    for (int ec = 0; ec < 8; ec++){
      float4 kvv = *(float4*)&kvs[d * 32 + ec * 4];
      acc[ec*4+0] += qd * kvv.x;
      acc[ec*4+1] += qd * kvv.y;
      acc[ec*4+2] += qd * kvv.z;
      acc[ec*4+3] += qd * kvv.w;
    }
  }

  const float f = 1.f + 1.f / (z + 1e-6f);
  u32 w[16];
  #pragma unroll
  for (int e = 0; e < 32; e++){
    long off = cbase + ((long)e << 12) + l;
    float val = (acc[e] * f - z * vms[e] + bf2f(Tb16[off])) * bf2f(O16[off]);
    u16 h = f2bf(val);
    if (e & 1) w[e >> 1] |= ((u32)h << 16);
    else       w[e >> 1] = h;
  }
  long ob = (((long)b << 12) << 8) + ((long)l << 8) + n * 32;
  #pragma unroll
  for (int j = 0; j < 4; j++)
    *(uint4*)&TT16[ob + j * 8] = make_uint4(w[4*j], w[4*j+1], w[4*j+2], w[4*j+3]);
}

// ---------------- proj GEMM: A hi/lo x B single, global_load_lds staging ----------------
__global__ __launch_bounds__(256) void k_gemmP(
    const u16* __restrict__ Phi_, const u16* __restrict__ Plo_,
    const u16* __restrict__ TT16, const float* __restrict__ bias,
    float* __restrict__ out)
{
  __shared__ __align__(16) u16 AhS[4096];
  __shared__ __align__(16) u16 AlS[4096];
  __shared__ __align__(16) u16 BhS[4096];
  const int tid = threadIdx.x;
  const int nt = blockIdx.x, mt = blockIdx.y, b = blockIdx.z;
  const int m0 = mt * 128, n0 = nt * 128;
  const int wave = tid >> 6, lane = tid & 63;
  const int wm = wave & 1, wn = wave >> 1, qu = lane >> 4, ln = lane & 15;

  const u16* bhp = TT16 + (((long)b << 12) << 8);
  const int l4 = lane >> 2, c4 = lane & 3;
  const int gch = (c4 ^ (l4 & 3)) * 8;
  const int fch = (qu ^ (ln & 3)) * 8;

  f32x4 acc[4][4];
  #pragma unroll
  for (int im = 0; im < 4; im++)
    #pragma unroll
    for (int in = 0; in < 4; in++)
      #pragma unroll
      for (int r = 0; r < 4; r++) acc[im][in][r] = 0.f;

  for (int kk = 0; kk < 256; kk += 32){
    #pragma unroll
    for (int t = 0; t < 2; t++){
      int rw = wave * 32 + t * 16;
      int ga = (m0 + rw + l4) * 256 + kk + gch;
      long gb = (long)(n0 + rw + l4) * 256 + kk + gch;
      gload16(&Phi_[ga], &AhS[rw * 32]);
      gload16(&Plo_[ga], &AlS[rw * 32]);
      gload16(&bhp[gb],  &BhS[rw * 32]);
    }
    __syncthreads();
    short8 fbh[4];
    #pragma unroll
    for (int in = 0; in < 4; in++){
      int row = wn * 64 + in * 16 + ln;
      fbh[in] = *(short8*)&BhS[row * 32 + fch];
    }
    #pragma unroll
    for (int im = 0; im < 4; im++){
      int row = wm * 64 + im * 16 + ln;
      short8 fah = *(short8*)&AhS[row * 32 + fch];
      short8 fal = *(short8*)&AlS[row * 32 + fch];
      #pragma unroll
      for (int in = 0; in < 4; in++){
        acc[im][in] = __builtin_amdgcn_mfma_f32_16x16x32_bf16(fah, fbh[in], acc[im][in], 0, 0, 0);
        acc[im][in] = __builtin_amdgcn_mfma_f32_16x16x32_bf16(fal, fbh[in], acc[im][in], 0, 0, 0);
      }
    }
    __syncthreads();
  }
  #pragma unroll
  for (int im = 0; im < 4; im++){
    int mbase = m0 + wm * 64 + im * 16 + qu * 4;
    #pragma unroll
    for (int r = 0; r < 4; r++){
      int m = mbase + r;
      float bia = bias[m];
      float* row = out + (((long)b * 256 + m) << 12);
      #pragma unroll
      for (int in = 0; in < 4; in++){
        int n = n0 + wn * 64 + in * 16 + ln;
        row[n] = acc[im][in][r] + bia;
      }
    }
  }
}

extern "C" void kernel_launch(void* const* d_in, const int* in_sizes, int n_in,
                              void* d_out, int out_size, void* d_ws, size_t ws_size,
                              hipStream_t stream)
{
  const float* x  = (const float*)d_in[0];
  const float* qw = (const float*)d_in[1];
  const float* qb = (const float*)d_in[2];
  const float* lw = (const float*)d_in[3];
  const float* lb = (const float*)d_in[4];
  const float* pw = (const float*)d_in[5];
  const float* pb = (const float*)d_in[6];

  u16* W    = (u16*)d_ws;
  u16* Q16  = W;
  u16* K16  = Q16 + 8388608;
  u16* V16  = K16 + 8388608;
  u16* O16  = V16 + 8388608;
  u16* Tb16 = O16 + 8388608;
  u16* XThi = Tb16 + 8388608;             // reused as TT16 after k_gemmA
  u16* XTlo = XThi + 8388608;
  u16* Whi  = XTlo + 8388608;
  u16* Wlo  = Whi + 262144;
  u16* Phi  = Wlo + 262144;
  u16* Plo  = Phi + 65536;
  float* KMb = (float*)(Plo + 65536);
  float* VMb = KMb + 2048;
  float* KVb = VMb + 2048;
  size_t total_bytes = (7ull*8388608 + 2*262144 + 2*65536) * 2 + (2048+2048+65536) * 4;
  if (ws_size < total_bytes) return;

  u16* TT16 = XThi;

  hipMemsetAsync(KMb, 0, 4096 * 4, stream);   // KMb + VMb raw sums
  k_prep<<<1024, 256, 0, stream>>>(qw, pw, Whi, Wlo, Phi, Plo);
  k_xt<<<dim3(64, 4, 8), 256, 0, stream>>>(x, XThi, XTlo);
  k_gemmA<<<dim3(32, 8, 8), 256, 0, stream>>>(Whi, Wlo, XThi, XTlo, qb,
                                              Q16, K16, V16, O16, KMb, VMb);
  k_kv<<<dim3(8, 8), 256, 0, stream>>>(K16, V16, KVb);
  k_lepe<<<dim3(4, 256, 8), 256, 0, stream>>>(V16, lw, lb, Tb16);
  k_res<<<dim3(16, 8, 8), 256, 0, stream>>>(Q16, KMb, KVb, VMb, O16, Tb16, TT16);
  k_gemmP<<<dim3(32, 2, 8), 256, 0, stream>>>(Phi, Plo, TT16, pb, (float*)d_out);
}

// Round 7
// 240.602 us; speedup vs baseline: 2.0446x; 1.1311x over previous
//
#include <hip/hip_runtime.h>
#include <math.h>

typedef unsigned short u16;
typedef unsigned int u32;
typedef __attribute__((ext_vector_type(8))) short short8;
typedef __attribute__((ext_vector_type(4))) float f32x4;
typedef __attribute__((ext_vector_type(16))) float f32x16;

// B=8, C=256, H=W=64, L=4096, NH=8, HD=32. Inputs/outputs fp32.
static constexpr float SCALE = 0.17677669529663687f;          // 1/sqrt(32)
static constexpr float C2    = 0.17677669529663687f / 4096.f; // (scale/L) = c^2

__device__ __forceinline__ float bf2f(u16 u){
  union { u32 i; float f; } v; v.i = ((u32)u) << 16; return v.f;
}
__device__ __forceinline__ u16 f2bf(float f){
  union { float fl; u32 i; } v; v.fl = f;
  u32 r = v.i + 0x7fffu + ((v.i >> 16) & 1u);   // RNE
  return (u16)(r >> 16);
}
__device__ __forceinline__ float eluP(float x){ return x > 0.f ? x + 1.f : __expf(x); }
__device__ __forceinline__ float rfreq(int j){
  const float t[8] = {1.f, 0.2682695795f, 0.0719685673f, 0.0193069773f,
                      0.0051794747f, 0.0013894955f, 0.0003727594f, 1e-4f};
  return t[j];
}
// async global->LDS, 16B per lane; lds base must be wave-uniform
__device__ __forceinline__ void gload16(const u16* g, u16* l){
  __builtin_amdgcn_global_load_lds(
      (const __attribute__((address_space(1))) u32*)g,
      (__attribute__((address_space(3))) u32*)l, 16, 0, 0);
}

// ---------------- weight split: fp32 -> bf16 hi/lo, keep [m][k] ----------------
__global__ __launch_bounds__(256) void k_prep(
    const float* __restrict__ qw, const float* __restrict__ pw,
    u16* __restrict__ Whi, u16* __restrict__ Wlo,
    u16* __restrict__ Phi, u16* __restrict__ Plo)
{
  int idx = blockIdx.x * 256 + threadIdx.x;
  if (idx < 262144){
    float v = qw[idx]; u16 h = f2bf(v);
    Whi[idx] = h; Wlo[idx] = f2bf(v - bf2f(h));
  }
  if (idx < 65536){
    float v = pw[idx]; u16 h = f2bf(v);
    Phi[idx] = h; Plo[idx] = f2bf(v - bf2f(h));
  }
}

// ---------------- x [b][c][l] fp32 -> XT [b][l][c] single bf16 ----------------
__global__ __launch_bounds__(256) void k_xt(
    const float* __restrict__ x, u16* __restrict__ XT)
{
  __shared__ float t[64][65];
  int l0 = blockIdx.x * 64, c0 = blockIdx.y * 64, b = blockIdx.z;
  const float* xp = x + (((long)b * 256 + c0) << 12) + l0;
  #pragma unroll
  for (int rep = 0; rep < 4; rep++){
    int idx = threadIdx.x + rep * 256;
    int r = idx >> 4, ch = (idx & 15) * 4;
    float4 f = *(const float4*)&xp[((long)r << 12) + ch];
    t[r][ch] = f.x; t[r][ch+1] = f.y; t[r][ch+2] = f.z; t[r][ch+3] = f.w;
  }
  __syncthreads();
  int r2 = threadIdx.x >> 2, c8 = (threadIdx.x & 3) * 16;
  u32 w[8];
  #pragma unroll
  for (int j = 0; j < 8; j++){
    float v0 = t[c8 + 2*j][r2], v1 = t[c8 + 2*j + 1][r2];
    w[j] = (u32)f2bf(v0) | ((u32)f2bf(v1) << 16);
  }
  long ob = (((long)b << 12) << 8) + ((long)(l0 + r2) << 8) + c0 + c8;
  *(uint4*)&XT[ob]     = make_uint4(w[0], w[1], w[2], w[3]);
  *(uint4*)&XT[ob + 8] = make_uint4(w[4], w[5], w[6], w[7]);
}

// ---------------- qkvo GEMM: (Whi+Wlo) x single-bf16 B, 2 MFMA/chunk ----------------
// LDS tiles packed [128][32] u16, XOR chunk swizzle: LDS chunk c of row r = global chunk c^(r&3)
__global__ __launch_bounds__(256) void k_gemmA(
    const u16* __restrict__ Whi_, const u16* __restrict__ Wlo_,
    const u16* __restrict__ Bh_,
    const float* __restrict__ bias,
    u16* __restrict__ Q16, u16* __restrict__ K16,
    u16* __restrict__ V16, u16* __restrict__ O16,
    float* __restrict__ KMb, float* __restrict__ VMb)
{
  __shared__ __align__(16) u16 AhS[4096];
  __shared__ __align__(16) u16 AlS[4096];
  __shared__ __align__(16) u16 BhS[4096];
  __shared__ float scs[2][8][64];
  const int tid = threadIdx.x;
  const int nt = blockIdx.x, mt = blockIdx.y, b = blockIdx.z;
  const int m0 = mt * 128, n0 = nt * 128;
  const int wave = tid >> 6, lane = tid & 63;
  const int wm = wave & 1, wn = wave >> 1, qu = lane >> 4, ln = lane & 15;

  #pragma unroll
  for (int r = 0; r < 2; r++){
    int idx = tid + r * 256;
    int jj = idx >> 6, pp = idx & 63;
    float sn, cs; sincosf(rfreq(jj) * (float)pp, &sn, &cs);
    scs[0][jj][pp] = sn; scs[1][jj][pp] = cs;
  }

  const u16* bhp = Bh_ + (((long)b << 12) << 8);

  // staging lane geometry
  const int l4 = lane >> 2, c4 = lane & 3;
  const int gch = (c4 ^ (l4 & 3)) * 8;            // swizzled global col chunk
  const int fch = (qu ^ (ln & 3)) * 8;            // fragment read swizzle

  f32x4 acc[4][4];
  #pragma unroll
  for (int im = 0; im < 4; im++)
    #pragma unroll
    for (int in = 0; in < 4; in++)
      #pragma unroll
      for (int r = 0; r < 4; r++) acc[im][in][r] = 0.f;

  for (int kk = 0; kk < 256; kk += 32){
    #pragma unroll
    for (int t = 0; t < 2; t++){
      int rw = wave * 32 + t * 16;
      int ga = (m0 + rw + l4) * 256 + kk + gch;
      long gb = (long)(n0 + rw + l4) * 256 + kk + gch;
      gload16(&Whi_[ga], &AhS[rw * 32]);
      gload16(&Wlo_[ga], &AlS[rw * 32]);
      gload16(&bhp[gb],  &BhS[rw * 32]);
    }
    __syncthreads();
    short8 fbh[4];
    #pragma unroll
    for (int in = 0; in < 4; in++){
      int row = wn * 64 + in * 16 + ln;
      fbh[in] = *(short8*)&BhS[row * 32 + fch];
    }
    #pragma unroll
    for (int im = 0; im < 4; im++){
      int row = wm * 64 + im * 16 + ln;
      short8 fah = *(short8*)&AhS[row * 32 + fch];
      short8 fal = *(short8*)&AlS[row * 32 + fch];
      #pragma unroll
      for (int in = 0; in < 4; in++){
        acc[im][in] = __builtin_amdgcn_mfma_f32_16x16x32_bf16(fah, fbh[in], acc[im][in], 0, 0, 0);
        acc[im][in] = __builtin_amdgcn_mfma_f32_16x16x32_bf16(fal, fbh[in], acc[im][in], 0, 0, 0);
      }
    }
    __syncthreads();
  }

  // epilogue: C/D layout col = lane&15 (n), row = quad*4 + reg (m)
  const int range = m0 >> 8;                 // 0:q 1:k 2:v 3:o (block-uniform)
  u16* dst = (range == 0) ? Q16 : (range == 1) ? K16 : (range == 2) ? V16 : O16;
  #pragma unroll
  for (int im = 0; im < 4; im++){
    const int mb = m0 + wm * 64 + im * 16 + qu * 4;
    float v[4][4];
    #pragma unroll
    for (int r = 0; r < 4; r++){
      float bia = bias[mb + r];
      #pragma unroll
      for (int in = 0; in < 4; in++){
        float t = acc[im][in][r] + bia;
        v[r][in] = (range < 2) ? eluP(t) : t;
      }
    }
    if (range == 1 || range == 2){
      float* mbuf = (range == 1) ? KMb : VMb;
      #pragma unroll
      for (int r = 0; r < 4; r++){
        float s = v[r][0] + v[r][1] + v[r][2] + v[r][3];
        s += __shfl_xor(s, 1); s += __shfl_xor(s, 2);
        s += __shfl_xor(s, 4); s += __shfl_xor(s, 8);
        if (ln == 0) atomicAdd(&mbuf[b * 256 + ((mb + r) & 255)], s);
      }
    }
    if (range == 1){
      const int p0 = (mb & 31) >> 1;
      #pragma unroll
      for (int half = 0; half < 2; half++){
        int p = p0 + half, j = p & 7;
        #pragma unroll
        for (int in = 0; in < 4; in++){
          int n = n0 + wn * 64 + in * 16 + ln;
          int pos = (p < 8) ? (n >> 6) : (n & 63);
          float sn = scs[0][j][pos], cs = scs[1][j][pos];
          float a = v[2*half][in], bb = v[2*half+1][in];
          v[2*half][in]   = a * cs - bb * sn;
          v[2*half+1][in] = bb * cs + a * sn;
        }
      }
    }
    #pragma unroll
    for (int r = 0; r < 4; r++){
      u16* rowp = dst + (((long)b * 256 + ((mb + r) & 255)) << 12);
      #pragma unroll
      for (int in = 0; in < 4; in++){
        int n = n0 + wn * 64 + in * 16 + ln;
        rowp[n] = f2bf(v[r][in]);
      }
    }
  }
}

// ---------------- kv via MFMA (unchanged) ----------------
__global__ __launch_bounds__(256) void k_kv(
    const u16* __restrict__ K16, const u16* __restrict__ V16, float* __restrict__ KVb)
{
  __shared__ float red[4][1024];
  const int n = blockIdx.x, b = blockIdx.y;
  const int tid = threadIdx.x, wave = tid >> 6, lane = tid & 63;
  const u16* kp = K16 + (((long)(b * 256 + n * 32)) << 12);
  const u16* vp = V16 + (((long)(b * 256 + n * 32)) << 12);
  const int m = lane & 31, kh = lane >> 5;
  const long row = ((long)m << 12);

  f32x16 acc;
  #pragma unroll
  for (int r = 0; r < 16; r++) acc[r] = 0.f;
  #pragma unroll 4
  for (int it = 0; it < 64; it++){
    int l = wave * 1024 + it * 16 + kh * 8;
    short8 a  = *(const short8*)&kp[row + l];
    short8 bf = *(const short8*)&vp[row + l];
    acc = __builtin_amdgcn_mfma_f32_32x32x16_bf16(a, bf, acc, 0, 0, 0);
  }
  #pragma unroll
  for (int reg = 0; reg < 16; reg++){
    int rr = (reg & 3) + 8 * (reg >> 2) + 4 * kh;
    red[wave][rr * 32 + m] = acc[reg];
  }
  __syncthreads();
  #pragma unroll
  for (int i = tid; i < 1024; i += 256){
    float s = red[0][i] + red[1][i] + red[2][i] + red[3][i];
    KVb[(((long)b * 8 + n) << 10) + i] = s * C2;
  }
}

// ---------------- lepe (unchanged) ----------------
__global__ __launch_bounds__(256) void k_lepe(
    const u16* __restrict__ V16, const float* __restrict__ lw,
    const float* __restrict__ lb, u16* __restrict__ Tb16)
{
  __shared__ float tile[20][68];
  __shared__ float wl[25];
  int ht = blockIdx.x, ch = blockIdx.y, b = blockIdx.z;
  int h0 = ht * 16;
  const u16* vp = V16 + (((long)b * 256 + ch) << 12);
  if (threadIdx.x < 25) wl[threadIdx.x] = lw[ch * 25 + threadIdx.x];
  for (int idx = threadIdx.x; idx < 20 * 68; idx += 256){
    int r = idx / 68, c = idx % 68;
    int gh = h0 + r - 2, gw = c - 2;
    float v = 0.f;
    if (gh >= 0 && gh < 64 && gw >= 0 && gw < 64) v = bf2f(vp[(gh << 6) + gw]);
    tile[r][c] = v;
  }
  __syncthreads();
  const float bia = lb[ch];
  #pragma unroll
  for (int r2 = 0; r2 < 4; r2++){
    int idx = threadIdx.x + r2 * 256;
    int oh = idx >> 6, ow = idx & 63;
    float s = bia;
    #pragma unroll
    for (int i = 0; i < 5; i++)
      #pragma unroll
      for (int j = 0; j < 5; j++) s += tile[oh + i][ow + j] * wl[i * 5 + j];
    Tb16[(((long)b * 256 + ch) << 12) + ((h0 + oh) << 6) + ow] = f2bf(s);
  }
}

// ---------------- res (+fused z) (unchanged) ----------------
__global__ __launch_bounds__(256) void k_res(
    const u16* __restrict__ Q16, const float* __restrict__ KMb,
    const float* __restrict__ KVb, const float* __restrict__ VMb,
    const u16* __restrict__ O16, const u16* __restrict__ Tb16,
    u16* __restrict__ TT16)
{
  __shared__ __align__(16) float kvs[1024];
  __shared__ float scs[2][8][64];
  __shared__ float kms[32], vms[32];
  const int b = blockIdx.z, n = blockIdx.y, tid = threadIdx.x;
  #pragma unroll
  for (int r = 0; r < 2; r++){
    int idx = tid + r * 256;
    int jj = idx >> 6, pp = idx & 63;
    float sn, cs; sincosf(rfreq(jj) * (float)pp, &sn, &cs);
    scs[0][jj][pp] = sn; scs[1][jj][pp] = cs;
  }
  {
    const float* kv = KVb + (((long)b * 8 + n) << 10);
    #pragma unroll
    for (int r = 0; r < 4; r++) kvs[tid + r * 256] = kv[tid + r * 256];
    if (tid < 32){
      kms[tid] = KMb[b * 256 + n * 32 + tid] * (1.f / 4096.f);
      vms[tid] = VMb[b * 256 + n * 32 + tid] * (1.f / 4096.f);
    }
  }
  __syncthreads();

  const int l = blockIdx.x * 256 + tid;
  const long cbase = ((long)(b * 256 + n * 32)) << 12;

  float q[32];
  #pragma unroll
  for (int d = 0; d < 32; d++) q[d] = bf2f(Q16[cbase + ((long)d << 12) + l]);
  float z = 0.f;
  #pragma unroll
  for (int d = 0; d < 32; d++) z += q[d] * kms[d];
  z *= SCALE;
  #pragma unroll
  for (int p = 0; p < 16; p++){
    int pos = (p < 8) ? (l >> 6) : (l & 63);
    float sn = scs[0][p & 7][pos], cs = scs[1][p & 7][pos];
    float q0 = q[2*p], q1 = q[2*p+1];
    q[2*p]   = q0 * cs - q1 * sn;
    q[2*p+1] = q1 * cs + q0 * sn;
  }

  float acc[32];
  #pragma unroll
  for (int e = 0; e < 32; e++) acc[e] = 0.f;
  #pragma unroll 8
  for (int d = 0; d < 32; d++){
    float qd = q[d];
    #pragma unroll
    for (int ec = 0; ec < 8; ec++){
      float4 kvv = *(float4*)&kvs[d * 32 + ec * 4];
      acc[ec*4+0] += qd * kvv.x;
      acc[ec*4+1] += qd * kvv.y;
      acc[ec*4+2] += qd * kvv.z;
      acc[ec*4+3] += qd * kvv.w;
    }
  }

  const float f = 1.f + 1.f / (z + 1e-6f);
  u32 w[16];
  #pragma unroll
  for (int e = 0; e < 32; e++){
    long off = cbase + ((long)e << 12) + l;
    float val = (acc[e] * f - z * vms[e] + bf2f(Tb16[off])) * bf2f(O16[off]);
    u16 h = f2bf(val);
    if (e & 1) w[e >> 1] |= ((u32)h << 16);
    else       w[e >> 1] = h;
  }
  long ob = (((long)b << 12) << 8) + ((long)l << 8) + n * 32;
  #pragma unroll
  for (int j = 0; j < 4; j++)
    *(uint4*)&TT16[ob + j * 8] = make_uint4(w[4*j], w[4*j+1], w[4*j+2], w[4*j+3]);
}

// ---------------- proj GEMM: A hi/lo x B single, global_load_lds staging ----------------
__global__ __launch_bounds__(256) void k_gemmP(
    const u16* __restrict__ Phi_, const u16* __restrict__ Plo_,
    const u16* __restrict__ TT16, const float* __restrict__ bias,
    float* __restrict__ out)
{
  __shared__ __align__(16) u16 AhS[4096];
  __shared__ __align__(16) u16 AlS[4096];
  __shared__ __align__(16) u16 BhS[4096];
  const int tid = threadIdx.x;
  const int nt = blockIdx.x, mt = blockIdx.y, b = blockIdx.z;
  const int m0 = mt * 128, n0 = nt * 128;
  const int wave = tid >> 6, lane = tid & 63;
  const int wm = wave & 1, wn = wave >> 1, qu = lane >> 4, ln = lane & 15;

  const u16* bhp = TT16 + (((long)b << 12) << 8);
  const int l4 = lane >> 2, c4 = lane & 3;
  const int gch = (c4 ^ (l4 & 3)) * 8;
  const int fch = (qu ^ (ln & 3)) * 8;

  f32x4 acc[4][4];
  #pragma unroll
  for (int im = 0; im < 4; im++)
    #pragma unroll
    for (int in = 0; in < 4; in++)
      #pragma unroll
      for (int r = 0; r < 4; r++) acc[im][in][r] = 0.f;

  for (int kk = 0; kk < 256; kk += 32){
    #pragma unroll
    for (int t = 0; t < 2; t++){
      int rw = wave * 32 + t * 16;
      int ga = (m0 + rw + l4) * 256 + kk + gch;
      long gb = (long)(n0 + rw + l4) * 256 + kk + gch;
      gload16(&Phi_[ga], &AhS[rw * 32]);
      gload16(&Plo_[ga], &AlS[rw * 32]);
      gload16(&bhp[gb],  &BhS[rw * 32]);
    }
    __syncthreads();
    short8 fbh[4];
    #pragma unroll
    for (int in = 0; in < 4; in++){
      int row = wn * 64 + in * 16 + ln;
      fbh[in] = *(short8*)&BhS[row * 32 + fch];
    }
    #pragma unroll
    for (int im = 0; im < 4; im++){
      int row = wm * 64 + im * 16 + ln;
      short8 fah = *(short8*)&AhS[row * 32 + fch];
      short8 fal = *(short8*)&AlS[row * 32 + fch];
      #pragma unroll
      for (int in = 0; in < 4; in++){
        acc[im][in] = __builtin_amdgcn_mfma_f32_16x16x32_bf16(fah, fbh[in], acc[im][in], 0, 0, 0);
        acc[im][in] = __builtin_amdgcn_mfma_f32_16x16x32_bf16(fal, fbh[in], acc[im][in], 0, 0, 0);
      }
    }
    __syncthreads();
  }
  #pragma unroll
  for (int im = 0; im < 4; im++){
    int mbase = m0 + wm * 64 + im * 16 + qu * 4;
    #pragma unroll
    for (int r = 0; r < 4; r++){
      int m = mbase + r;
      float bia = bias[m];
      float* row = out + (((long)b * 256 + m) << 12);
      #pragma unroll
      for (int in = 0; in < 4; in++){
        int n = n0 + wn * 64 + in * 16 + ln;
        row[n] = acc[im][in][r] + bia;
      }
    }
  }
}

extern "C" void kernel_launch(void* const* d_in, const int* in_sizes, int n_in,
                              void* d_out, int out_size, void* d_ws, size_t ws_size,
                              hipStream_t stream)
{
  const float* x  = (const float*)d_in[0];
  const float* qw = (const float*)d_in[1];
  const float* qb = (const float*)d_in[2];
  const float* lw = (const float*)d_in[3];
  const float* lb = (const float*)d_in[4];
  const float* pw = (const float*)d_in[5];
  const float* pb = (const float*)d_in[6];

  u16* W    = (u16*)d_ws;
  u16* Q16  = W;
  u16* K16  = Q16 + 8388608;
  u16* V16  = K16 + 8388608;
  u16* O16  = V16 + 8388608;
  u16* Tb16 = O16 + 8388608;
  u16* XT   = Tb16 + 8388608;             // reused as TT16 after k_gemmA
  u16* Whi  = XT + 8388608;
  u16* Wlo  = Whi + 262144;
  u16* Phi  = Wlo + 262144;
  u16* Plo  = Phi + 65536;
  float* KMb = (float*)(Plo + 65536);
  float* VMb = KMb + 2048;
  float* KVb = VMb + 2048;
  size_t total_bytes = (6ull*8388608 + 2*262144 + 2*65536) * 2 + (2048+2048+65536) * 4;
  if (ws_size < total_bytes) return;

  u16* TT16 = XT;

  hipMemsetAsync(KMb, 0, 4096 * 4, stream);   // KMb + VMb raw sums
  k_prep<<<1024, 256, 0, stream>>>(qw, pw, Whi, Wlo, Phi, Plo);
  k_xt<<<dim3(64, 4, 8), 256, 0, stream>>>(x, XT);
  k_gemmA<<<dim3(32, 8, 8), 256, 0, stream>>>(Whi, Wlo, XT, qb,
                                              Q16, K16, V16, O16, KMb, VMb);
  k_kv<<<dim3(8, 8), 256, 0, stream>>>(K16, V16, KVb);
  k_lepe<<<dim3(4, 256, 8), 256, 0, stream>>>(V16, lw, lb, Tb16);
  k_res<<<dim3(16, 8, 8), 256, 0, stream>>>(Q16, KMb, KVb, VMb, O16, Tb16, TT16);
  k_gemmP<<<dim3(32, 2, 8), 256, 0, stream>>>(Phi, Plo, TT16, pb, (float*)d_out);
}

// Round 8
// 233.812 us; speedup vs baseline: 2.1040x; 1.0290x over previous
//
#include <hip/hip_runtime.h>
#include <math.h>

typedef unsigned short u16;
typedef unsigned int u32;
typedef unsigned long long u64;
typedef __attribute__((ext_vector_type(8))) short short8;
typedef __attribute__((ext_vector_type(4))) float f32x4;
typedef __attribute__((ext_vector_type(16))) float f32x16;

// B=8, C=256, H=W=64, L=4096, NH=8, HD=32. Inputs/outputs fp32.
static constexpr float SCALE = 0.17677669529663687f;          // 1/sqrt(32)
static constexpr float C2    = 0.17677669529663687f / 4096.f; // (scale/L) = c^2

__device__ __forceinline__ float bf2f(u16 u){
  union { u32 i; float f; } v; v.i = ((u32)u) << 16; return v.f;
}
__device__ __forceinline__ u16 f2bf(float f){
  union { float fl; u32 i; } v; v.fl = f;
  u32 r = v.i + 0x7fffu + ((v.i >> 16) & 1u);   // RNE
  return (u16)(r >> 16);
}
__device__ __forceinline__ float eluP(float x){ return x > 0.f ? x + 1.f : __expf(x); }
__device__ __forceinline__ float rfreq(int j){
  const float t[8] = {1.f, 0.2682695795f, 0.0719685673f, 0.0193069773f,
                      0.0051794747f, 0.0013894955f, 0.0003727594f, 1e-4f};
  return t[j];
}
// async global->LDS, 16B per lane; lds base must be wave-uniform
__device__ __forceinline__ void gload16(const u16* g, u16* l){
  __builtin_amdgcn_global_load_lds(
      (const __attribute__((address_space(1))) u32*)g,
      (__attribute__((address_space(3))) u32*)l, 16, 0, 0);
}

// ---------------- pre: x transpose + weight split + mean-buffer zero (merged) ----------------
// grid (64, 4, 12): z<8 -> xt for batch z; z>=8 -> weight prep (1024 virtual blocks)
__global__ __launch_bounds__(256) void k_pre(
    const float* __restrict__ x, const float* __restrict__ qw, const float* __restrict__ pw,
    u16* __restrict__ XT, u16* __restrict__ Whi, u16* __restrict__ Wlo,
    u16* __restrict__ Phi, u16* __restrict__ Plo, float* __restrict__ KM0)
{
  if (blockIdx.z < 8){
    __shared__ float t[64][65];
    int l0 = blockIdx.x * 64, c0 = blockIdx.y * 64, b = blockIdx.z;
    const float* xp = x + (((long)b * 256 + c0) << 12) + l0;
    #pragma unroll
    for (int rep = 0; rep < 4; rep++){
      int idx = threadIdx.x + rep * 256;
      int r = idx >> 4, ch = (idx & 15) * 4;
      float4 f = *(const float4*)&xp[((long)r << 12) + ch];
      t[r][ch] = f.x; t[r][ch+1] = f.y; t[r][ch+2] = f.z; t[r][ch+3] = f.w;
    }
    __syncthreads();
    int r2 = threadIdx.x >> 2, c8 = (threadIdx.x & 3) * 16;
    u32 w[8];
    #pragma unroll
    for (int j = 0; j < 8; j++){
      float v0 = t[c8 + 2*j][r2], v1 = t[c8 + 2*j + 1][r2];
      w[j] = (u32)f2bf(v0) | ((u32)f2bf(v1) << 16);
    }
    long ob = (((long)b << 12) << 8) + ((long)(l0 + r2) << 8) + c0 + c8;
    *(uint4*)&XT[ob]     = make_uint4(w[0], w[1], w[2], w[3]);
    *(uint4*)&XT[ob + 8] = make_uint4(w[4], w[5], w[6], w[7]);
  } else {
    int bid = (blockIdx.z - 8) * 256 + blockIdx.y * 64 + blockIdx.x;   // 0..1023
    int idx = bid * 256 + threadIdx.x;
    if (idx < 262144){
      float v = qw[idx]; u16 h = f2bf(v);
      Whi[idx] = h; Wlo[idx] = f2bf(v - bf2f(h));
    }
    if (idx < 65536){
      float v = pw[idx]; u16 h = f2bf(v);
      Phi[idx] = h; Plo[idx] = f2bf(v - bf2f(h));
    }
    if (bid == 0){
      #pragma unroll
      for (int i = 0; i < 16; i++) KM0[threadIdx.x + i * 256] = 0.f;
    }
  }
}

// ---------------- qkvo GEMM: (Whi+Wlo) x single-bf16 B, 2 MFMA/chunk ----------------
// LDS tiles packed [128][32] u16, XOR chunk swizzle: LDS chunk c of row r = global chunk c^(r&3)
__global__ __launch_bounds__(256) void k_gemmA(
    const u16* __restrict__ Whi_, const u16* __restrict__ Wlo_,
    const u16* __restrict__ Bh_,
    const float* __restrict__ bias,
    u16* __restrict__ Q16, u16* __restrict__ K16,
    u16* __restrict__ V16, u16* __restrict__ O16,
    float* __restrict__ KMb, float* __restrict__ VMb)
{
  __shared__ __align__(16) u16 AhS[4096];
  __shared__ __align__(16) u16 AlS[4096];
  __shared__ __align__(16) u16 BhS[4096];
  __shared__ float scs[2][8][64];
  const int tid = threadIdx.x;
  const int nt = blockIdx.x, mt = blockIdx.y, b = blockIdx.z;
  const int m0 = mt * 128, n0 = nt * 128;
  const int wave = tid >> 6, lane = tid & 63;
  const int wm = wave & 1, wn = wave >> 1, qu = lane >> 4, ln = lane & 15;

  #pragma unroll
  for (int r = 0; r < 2; r++){
    int idx = tid + r * 256;
    int jj = idx >> 6, pp = idx & 63;
    float sn, cs; sincosf(rfreq(jj) * (float)pp, &sn, &cs);
    scs[0][jj][pp] = sn; scs[1][jj][pp] = cs;
  }

  const u16* bhp = Bh_ + (((long)b << 12) << 8);

  const int l4 = lane >> 2, c4 = lane & 3;
  const int gch = (c4 ^ (l4 & 3)) * 8;            // swizzled global col chunk
  const int fch = (qu ^ (ln & 3)) * 8;            // fragment read swizzle

  f32x4 acc[4][4];
  #pragma unroll
  for (int im = 0; im < 4; im++)
    #pragma unroll
    for (int in = 0; in < 4; in++)
      #pragma unroll
      for (int r = 0; r < 4; r++) acc[im][in][r] = 0.f;

  for (int kk = 0; kk < 256; kk += 32){
    #pragma unroll
    for (int t = 0; t < 2; t++){
      int rw = wave * 32 + t * 16;
      int ga = (m0 + rw + l4) * 256 + kk + gch;
      long gb = (long)(n0 + rw + l4) * 256 + kk + gch;
      gload16(&Whi_[ga], &AhS[rw * 32]);
      gload16(&Wlo_[ga], &AlS[rw * 32]);
      gload16(&bhp[gb],  &BhS[rw * 32]);
    }
    __syncthreads();
    short8 fbh[4];
    #pragma unroll
    for (int in = 0; in < 4; in++){
      int row = wn * 64 + in * 16 + ln;
      fbh[in] = *(short8*)&BhS[row * 32 + fch];
    }
    #pragma unroll
    for (int im = 0; im < 4; im++){
      int row = wm * 64 + im * 16 + ln;
      short8 fah = *(short8*)&AhS[row * 32 + fch];
      short8 fal = *(short8*)&AlS[row * 32 + fch];
      #pragma unroll
      for (int in = 0; in < 4; in++){
        acc[im][in] = __builtin_amdgcn_mfma_f32_16x16x32_bf16(fah, fbh[in], acc[im][in], 0, 0, 0);
        acc[im][in] = __builtin_amdgcn_mfma_f32_16x16x32_bf16(fal, fbh[in], acc[im][in], 0, 0, 0);
      }
    }
    __syncthreads();
  }

  // epilogue: C/D layout col = lane&15 (n), row = quad*4 + reg (m)
  const int range = m0 >> 8;                 // 0:q 1:k 2:v 3:o (block-uniform)
  u16* dst = (range == 0) ? Q16 : (range == 1) ? K16 : (range == 2) ? V16 : O16;
  #pragma unroll
  for (int im = 0; im < 4; im++){
    const int mb = m0 + wm * 64 + im * 16 + qu * 4;
    float v[4][4];
    #pragma unroll
    for (int r = 0; r < 4; r++){
      float bia = bias[mb + r];
      #pragma unroll
      for (int in = 0; in < 4; in++){
        float t = acc[im][in][r] + bia;
        v[r][in] = (range < 2) ? eluP(t) : t;
      }
    }
    if (range == 1 || range == 2){
      float* mbuf = (range == 1) ? KMb : VMb;
      #pragma unroll
      for (int r = 0; r < 4; r++){
        float s = v[r][0] + v[r][1] + v[r][2] + v[r][3];
        s += __shfl_xor(s, 1); s += __shfl_xor(s, 2);
        s += __shfl_xor(s, 4); s += __shfl_xor(s, 8);
        if (ln == 0) atomicAdd(&mbuf[b * 256 + ((mb + r) & 255)], s);
      }
    }
    if (range == 1){
      const int p0 = (mb & 31) >> 1;
      #pragma unroll
      for (int half = 0; half < 2; half++){
        int p = p0 + half, j = p & 7;
        #pragma unroll
        for (int in = 0; in < 4; in++){
          int n = n0 + wn * 64 + in * 16 + ln;
          int pos = (p < 8) ? (n >> 6) : (n & 63);
          float sn = scs[0][j][pos], cs = scs[1][j][pos];
          float a = v[2*half][in], bb = v[2*half+1][in];
          v[2*half][in]   = a * cs - bb * sn;
          v[2*half+1][in] = bb * cs + a * sn;
        }
      }
    }
    #pragma unroll
    for (int r = 0; r < 4; r++){
      u16* rowp = dst + (((long)b * 256 + ((mb + r) & 255)) << 12);
      #pragma unroll
      for (int in = 0; in < 4; in++){
        int n = n0 + wn * 64 + in * 16 + ln;
        rowp[n] = f2bf(v[r][in]);
      }
    }
  }
}

// ---------------- mid: lepe + kv merged into one launch ----------------
// grid (4, 258, 8): y<256 -> lepe(ht=x, ch=y, b=z); y>=256 -> kv block
__global__ __launch_bounds__(256) void k_mid(
    const u16* __restrict__ K16, const u16* __restrict__ V16,
    const float* __restrict__ lw, const float* __restrict__ lb,
    u16* __restrict__ Tb16, float* __restrict__ KVb)
{
  if (blockIdx.y < 256){
    __shared__ float tile[20][68];
    __shared__ float wl[25];
    int ht = blockIdx.x, ch = blockIdx.y, b = blockIdx.z;
    int h0 = ht * 16;
    const u16* vp = V16 + (((long)b * 256 + ch) << 12);
    if (threadIdx.x < 25) wl[threadIdx.x] = lw[ch * 25 + threadIdx.x];
    for (int idx = threadIdx.x; idx < 20 * 68; idx += 256){
      int r = idx / 68, c = idx % 68;
      int gh = h0 + r - 2, gw = c - 2;
      float v = 0.f;
      if (gh >= 0 && gh < 64 && gw >= 0 && gw < 64) v = bf2f(vp[(gh << 6) + gw]);
      tile[r][c] = v;
    }
    __syncthreads();
    const float bia = lb[ch];
    #pragma unroll
    for (int r2 = 0; r2 < 4; r2++){
      int idx = threadIdx.x + r2 * 256;
      int oh = idx >> 6, ow = idx & 63;
      float s = bia;
      #pragma unroll
      for (int i = 0; i < 5; i++)
        #pragma unroll
        for (int j = 0; j < 5; j++) s += tile[oh + i][ow + j] * wl[i * 5 + j];
      Tb16[(((long)b * 256 + ch) << 12) + ((h0 + oh) << 6) + ow] = f2bf(s);
    }
  } else {
    __shared__ float red[4][1024];
    int kvIdx = (blockIdx.y - 256) * 32 + blockIdx.z * 4 + blockIdx.x;  // 0..63
    int n = kvIdx & 7, b = kvIdx >> 3;
    const int tid = threadIdx.x, wave = tid >> 6, lane = tid & 63;
    const u16* kp = K16 + (((long)(b * 256 + n * 32)) << 12);
    const u16* vp = V16 + (((long)(b * 256 + n * 32)) << 12);
    const int m = lane & 31, kh = lane >> 5;
    const long row = ((long)m << 12);

    f32x16 acc;
    #pragma unroll
    for (int r = 0; r < 16; r++) acc[r] = 0.f;
    #pragma unroll 4
    for (int it = 0; it < 64; it++){
      int l = wave * 1024 + it * 16 + kh * 8;
      short8 a  = *(const short8*)&kp[row + l];
      short8 bf = *(const short8*)&vp[row + l];
      acc = __builtin_amdgcn_mfma_f32_32x32x16_bf16(a, bf, acc, 0, 0, 0);
    }
    #pragma unroll
    for (int reg = 0; reg < 16; reg++){
      int rr = (reg & 3) + 8 * (reg >> 2) + 4 * kh;
      red[wave][rr * 32 + m] = acc[reg];
    }
    __syncthreads();
    #pragma unroll
    for (int i = tid; i < 1024; i += 256){
      float s = red[0][i] + red[1][i] + red[2][i] + red[3][i];
      KVb[(((long)b * 8 + n) << 10) + i] = s * C2;
    }
  }
}

// ---------------- res (+fused z): coalesced TT store via LDS reorder ----------------
// grid (16 lt, 8 n, 8 b), 1 l per thread
__global__ __launch_bounds__(256) void k_res(
    const u16* __restrict__ Q16, const float* __restrict__ KMb,
    const float* __restrict__ KVb, const float* __restrict__ VMb,
    const u16* __restrict__ O16, const u16* __restrict__ Tb16,
    u16* __restrict__ TT16)
{
  __shared__ __align__(16) float kvs[1024];
  __shared__ float scs[2][8][64];
  __shared__ float kms[32], vms[32];
  __shared__ __align__(16) u64 tts[256 * 9];   // [l][8 u64 + 1 pad]
  const int b = blockIdx.z, n = blockIdx.y, tid = threadIdx.x;
  #pragma unroll
  for (int r = 0; r < 2; r++){
    int idx = tid + r * 256;
    int jj = idx >> 6, pp = idx & 63;
    float sn, cs; sincosf(rfreq(jj) * (float)pp, &sn, &cs);
    scs[0][jj][pp] = sn; scs[1][jj][pp] = cs;
  }
  {
    const float* kv = KVb + (((long)b * 8 + n) << 10);
    #pragma unroll
    for (int r = 0; r < 4; r++) kvs[tid + r * 256] = kv[tid + r * 256];
    if (tid < 32){
      kms[tid] = KMb[b * 256 + n * 32 + tid] * (1.f / 4096.f);
      vms[tid] = VMb[b * 256 + n * 32 + tid] * (1.f / 4096.f);
    }
  }
  __syncthreads();

  const int l0 = blockIdx.x * 256;
  const int l = l0 + tid;
  const long cbase = ((long)(b * 256 + n * 32)) << 12;

  float q[32];
  #pragma unroll
  for (int d = 0; d < 32; d++) q[d] = bf2f(Q16[cbase + ((long)d << 12) + l]);
  float z = 0.f;
  #pragma unroll
  for (int d = 0; d < 32; d++) z += q[d] * kms[d];
  z *= SCALE;
  #pragma unroll
  for (int p = 0; p < 16; p++){
    int pos = (p < 8) ? (l >> 6) : (l & 63);
    float sn = scs[0][p & 7][pos], cs = scs[1][p & 7][pos];
    float q0 = q[2*p], q1 = q[2*p+1];
    q[2*p]   = q0 * cs - q1 * sn;
    q[2*p+1] = q1 * cs + q0 * sn;
  }

  float acc[32];
  #pragma unroll
  for (int e = 0; e < 32; e++) acc[e] = 0.f;
  #pragma unroll 8
  for (int d = 0; d < 32; d++){
    float qd = q[d];
    #pragma unroll
    for (int ec = 0; ec < 8; ec++){
      float4 kvv = *(float4*)&kvs[d * 32 + ec * 4];
      acc[ec*4+0] += qd * kvv.x;
      acc[ec*4+1] += qd * kvv.y;
      acc[ec*4+2] += qd * kvv.z;
      acc[ec*4+3] += qd * kvv.w;
    }
  }

  const float f = 1.f + 1.f / (z + 1e-6f);
  u32 w[16];
  #pragma unroll
  for (int e = 0; e < 32; e++){
    long off = cbase + ((long)e << 12) + l;
    float val = (acc[e] * f - z * vms[e] + bf2f(Tb16[off])) * bf2f(O16[off]);
    u16 h = f2bf(val);
    if (e & 1) w[e >> 1] |= ((u32)h << 16);
    else       w[e >> 1] = h;
  }
  // stage 64 B/thread into LDS, then coalesced readout (16 rows x 64 B per wave-store)
  #pragma unroll
  for (int j = 0; j < 8; j++)
    tts[tid * 9 + j] = (u64)w[2*j] | ((u64)w[2*j+1] << 32);
  __syncthreads();
  #pragma unroll
  for (int it = 0; it < 4; it++){
    int row = (tid >> 2) + 64 * it;
    int cc = tid & 3;
    u64 a  = tts[row * 9 + cc * 2];
    u64 bb = tts[row * 9 + cc * 2 + 1];
    long orow = (((long)b << 12) << 8) + ((long)(l0 + row) << 8) + n * 32 + cc * 8;
    *(uint4*)&TT16[orow] = make_uint4((u32)a, (u32)(a >> 32), (u32)bb, (u32)(bb >> 32));
  }
}

// ---------------- proj GEMM: A hi/lo x B single, global_load_lds staging ----------------
__global__ __launch_bounds__(256) void k_gemmP(
    const u16* __restrict__ Phi_, const u16* __restrict__ Plo_,
    const u16* __restrict__ TT16, const float* __restrict__ bias,
    float* __restrict__ out)
{
  __shared__ __align__(16) u16 AhS[4096];
  __shared__ __align__(16) u16 AlS[4096];
  __shared__ __align__(16) u16 BhS[4096];
  const int tid = threadIdx.x;
  const int nt = blockIdx.x, mt = blockIdx.y, b = blockIdx.z;
  const int m0 = mt * 128, n0 = nt * 128;
  const int wave = tid >> 6, lane = tid & 63;
  const int wm = wave & 1, wn = wave >> 1, qu = lane >> 4, ln = lane & 15;

  const u16* bhp = TT16 + (((long)b << 12) << 8);
  const int l4 = lane >> 2, c4 = lane & 3;
  const int gch = (c4 ^ (l4 & 3)) * 8;
  const int fch = (qu ^ (ln & 3)) * 8;

  f32x4 acc[4][4];
  #pragma unroll
  for (int im = 0; im < 4; im++)
    #pragma unroll
    for (int in = 0; in < 4; in++)
      #pragma unroll
      for (int r = 0; r < 4; r++) acc[im][in][r] = 0.f;

  for (int kk = 0; kk < 256; kk += 32){
    #pragma unroll
    for (int t = 0; t < 2; t++){
      int rw = wave * 32 + t * 16;
      int ga = (m0 + rw + l4) * 256 + kk + gch;
      long gb = (long)(n0 + rw + l4) * 256 + kk + gch;
      gload16(&Phi_[ga], &AhS[rw * 32]);
      gload16(&Plo_[ga], &AlS[rw * 32]);
      gload16(&bhp[gb],  &BhS[rw * 32]);
    }
    __syncthreads();
    short8 fbh[4];
    #pragma unroll
    for (int in = 0; in < 4; in++){
      int row = wn * 64 + in * 16 + ln;
      fbh[in] = *(short8*)&BhS[row * 32 + fch];
    }
    #pragma unroll
    for (int im = 0; im < 4; im++){
      int row = wm * 64 + im * 16 + ln;
      short8 fah = *(short8*)&AhS[row * 32 + fch];
      short8 fal = *(short8*)&AlS[row * 32 + fch];
      #pragma unroll
      for (int in = 0; in < 4; in++){
        acc[im][in] = __builtin_amdgcn_mfma_f32_16x16x32_bf16(fah, fbh[in], acc[im][in], 0, 0, 0);
        acc[im][in] = __builtin_amdgcn_mfma_f32_16x16x32_bf16(fal, fbh[in], acc[im][in], 0, 0, 0);
      }
    }
    __syncthreads();
  }
  #pragma unroll
  for (int im = 0; im < 4; im++){
    int mbase = m0 + wm * 64 + im * 16 + qu * 4;
    #pragma unroll
    for (int r = 0; r < 4; r++){
      int m = mbase + r;
      float bia = bias[m];
      float* row = out + (((long)b * 256 + m) << 12);
      #pragma unroll
      for (int in = 0; in < 4; in++){
        int n = n0 + wn * 64 + in * 16 + ln;
        row[n] = acc[im][in][r] + bia;
      }
    }
  }
}

extern "C" void kernel_launch(void* const* d_in, const int* in_sizes, int n_in,
                              void* d_out, int out_size, void* d_ws, size_t ws_size,
                              hipStream_t stream)
{
  const float* x  = (const float*)d_in[0];
  const float* qw = (const float*)d_in[1];
  const float* qb = (const float*)d_in[2];
  const float* lw = (const float*)d_in[3];
  const float* lb = (const float*)d_in[4];
  const float* pw = (const float*)d_in[5];
  const float* pb = (const float*)d_in[6];

  u16* W    = (u16*)d_ws;
  u16* Q16  = W;
  u16* K16  = Q16 + 8388608;
  u16* V16  = K16 + 8388608;
  u16* O16  = V16 + 8388608;
  u16* Tb16 = O16 + 8388608;
  u16* XT   = Tb16 + 8388608;             // reused as TT16 after k_gemmA
  u16* Whi  = XT + 8388608;
  u16* Wlo  = Whi + 262144;
  u16* Phi  = Wlo + 262144;
  u16* Plo  = Phi + 65536;
  float* KMb = (float*)(Plo + 65536);
  float* VMb = KMb + 2048;
  float* KVb = VMb + 2048;
  size_t total_bytes = (6ull*8388608 + 2*262144 + 2*65536) * 2 + (2048+2048+65536) * 4;
  if (ws_size < total_bytes) return;

  u16* TT16 = XT;

  k_pre<<<dim3(64, 4, 12), 256, 0, stream>>>(x, qw, pw, XT, Whi, Wlo, Phi, Plo, KMb);
  k_gemmA<<<dim3(32, 8, 8), 256, 0, stream>>>(Whi, Wlo, XT, qb,
                                              Q16, K16, V16, O16, KMb, VMb);
  k_mid<<<dim3(4, 258, 8), 256, 0, stream>>>(K16, V16, lw, lb, Tb16, KVb);
  k_res<<<dim3(16, 8, 8), 256, 0, stream>>>(Q16, KMb, KVb, VMb, O16, Tb16, TT16);
  k_gemmP<<<dim3(32, 2, 8), 256, 0, stream>>>(Phi, Plo, TT16, pb, (float*)d_out);
}